// Round 1
// baseline (851.129 us; speedup 1.0000x reference)
//
#include <hip/hip_runtime.h>
#include <math.h>

// Problem constants: B=2, D=512, N=M=2048, H=8, K=V=64
#define BB 2
#define DDIM 512
#define NSEQ 2048
#define NHEAD 8

// ---------------------------------------------------------------------------
// Kernel 1: K/V projection.
// kk[b][m][j] = sum_d x[b][d][m] * kp[d][j];  vv likewise with vp.
// Lanes = j (coalesced weight reads); each thread handles 4 consecutive m via
// a wave-uniform float4 load of x[b][d][m0..m0+3].
// ---------------------------------------------------------------------------
__global__ __launch_bounds__(256) void kv_proj_kernel(
    const float* __restrict__ x, const float* __restrict__ kp,
    const float* __restrict__ vp, float* __restrict__ kk, float* __restrict__ vv)
{
    int tid = threadIdx.x;
    int j = tid & 63;
    int g = tid >> 6;
    int flat = blockIdx.x * 4 + g;        // over B*N/4 = 1024
    int b = flat >> 9;
    int m0 = (flat & 511) << 2;           // 4 m's per thread
    const float* xb = x + (size_t)b * DDIM * NSEQ;
    float aK0=0,aK1=0,aK2=0,aK3=0, aV0=0,aV1=0,aV2=0,aV3=0;
    for (int d = 0; d < DDIM; ++d) {
        float4 xv = *(const float4*)(xb + (size_t)d * NSEQ + m0);
        float kw = kp[d * 64 + j];
        float vw = vp[d * 64 + j];
        aK0 = fmaf(xv.x, kw, aK0); aV0 = fmaf(xv.x, vw, aV0);
        aK1 = fmaf(xv.y, kw, aK1); aV1 = fmaf(xv.y, vw, aV1);
        aK2 = fmaf(xv.z, kw, aK2); aV2 = fmaf(xv.z, vw, aV2);
        aK3 = fmaf(xv.w, kw, aK3); aV3 = fmaf(xv.w, vw, aV3);
    }
    size_t base = ((size_t)b * NSEQ + m0) * 64 + j;
    kk[base]        = aK0; vv[base]        = aV0;
    kk[base + 64]   = aK1; vv[base + 64]   = aV1;
    kk[base + 128]  = aK2; vv[base + 128]  = aV2;
    kk[base + 192]  = aK3; vv[base + 192]  = aV3;
}

// ---------------------------------------------------------------------------
// Kernel 2: transpose query_proj (H,K,D) -> qpT (H,D,K) so the q-projection
// reads weights coalesced (lane = k).
// ---------------------------------------------------------------------------
__global__ __launch_bounds__(256) void qp_transpose_kernel(
    const float* __restrict__ qp, float* __restrict__ qpT)
{
    int g = blockIdx.x * 256 + threadIdx.x;   // total H*512*64 = 262144
    int j = g & 63;
    int d = (g >> 6) & 511;
    int h = g >> 15;
    qpT[g] = qp[((size_t)(h * 64 + j)) * DDIM + d];
}

// ---------------------------------------------------------------------------
// Kernel 3: Q projection (with 1/sqrt(K) folded in).
// q[b][n][h][j] = 0.125 * sum_d x[b][d][n] * qpT[h][d][j]
// Each thread handles 4 consecutive n (shared weight load, float4 x load).
// ---------------------------------------------------------------------------
__global__ __launch_bounds__(256) void q_proj_kernel(
    const float* __restrict__ x, const float* __restrict__ qpT, float* __restrict__ q)
{
    int tid = threadIdx.x;
    int j = tid & 63;
    int sub = tid >> 6;
    int flat = blockIdx.x * 4 + sub;      // over B*(N/4)*H = 8192
    int h = flat & 7;
    int n4 = (flat >> 3) & 511;
    int b = flat >> 12;
    int n0 = n4 * 4;
    const float* xb = x + (size_t)b * DDIM * NSEQ;
    const float* w = qpT + (size_t)h * DDIM * 64 + j;
    float a0=0,a1=0,a2=0,a3=0;
    for (int d = 0; d < DDIM; ++d) {
        float4 xv = *(const float4*)(xb + (size_t)d * NSEQ + n0);
        float wv = w[d * 64];
        a0 = fmaf(xv.x, wv, a0);
        a1 = fmaf(xv.y, wv, a1);
        a2 = fmaf(xv.z, wv, a2);
        a3 = fmaf(xv.w, wv, a3);
    }
    const float qscale = 0.125f;  // 1/sqrt(64)
    q[(((size_t)b * NSEQ + n0 + 0) * NHEAD + h) * 64 + j] = a0 * qscale;
    q[(((size_t)b * NSEQ + n0 + 1) * NHEAD + h) * 64 + j] = a1 * qscale;
    q[(((size_t)b * NSEQ + n0 + 2) * NHEAD + h) * 64 + j] = a2 * qscale;
    q[(((size_t)b * NSEQ + n0 + 3) * NHEAD + h) * 64 + j] = a3 * qscale;
}

// ---------------------------------------------------------------------------
// Kernel 4: flash-style attention, fp32.
// Block = (b, h, 64 n-rows). 256 threads: row = tid&63, m-slice c = tid>>6.
// Thread owns q[64] and o[64] in registers; iterates m-tiles of 64 staged in
// LDS; thread c handles m%4==c within each tile (16 m's), chunked online
// softmax (one o-rescale per tile). 4 partial states merged via LDS at end.
// Output o[b][n][h][v] (unnormalized-then-normalized).
// ---------------------------------------------------------------------------
__global__ __launch_bounds__(256) void attn_kernel(
    const float* __restrict__ q, const float* __restrict__ kk,
    const float* __restrict__ vv, float* __restrict__ o)
{
    __shared__ float Klds[64 * 64];
    __shared__ float Vlds[64 * 64];
    __shared__ float olds[64 * 65];     // +1 pad: writes stride 65 -> 2-way max
    __shared__ float mred[4 * 64];
    __shared__ float lred[4 * 64];
    __shared__ float linv[64];

    int tid = threadIdx.x;
    int row = tid & 63;
    int c = tid >> 6;
    int b = blockIdx.z;
    int h = blockIdx.y;
    int n0 = blockIdx.x * 64;
    int n = n0 + row;

    float4 q4[16];
    const float4* qptr = (const float4*)(q + (((size_t)b * NSEQ + n) * NHEAD + h) * 64);
    #pragma unroll
    for (int i = 0; i < 16; ++i) q4[i] = qptr[i];

    float4 o4[16];
    #pragma unroll
    for (int i = 0; i < 16; ++i) o4[i] = make_float4(0.f, 0.f, 0.f, 0.f);
    float mi = -1e30f, li = 0.f;

    const float4* ksrc = (const float4*)(kk + ((size_t)b * NSEQ) * 64);
    const float4* vsrc = (const float4*)(vv + ((size_t)b * NSEQ) * 64);

    for (int mt = 0; mt < NSEQ / 64; ++mt) {
        __syncthreads();
        float4* kd = (float4*)Klds;
        float4* vd = (float4*)Vlds;
        #pragma unroll
        for (int i = 0; i < 4; ++i) {
            int idx = tid + i * 256;           // 1024 float4 per tile
            kd[idx] = ksrc[(size_t)mt * 1024 + idx];
            vd[idx] = vsrc[(size_t)mt * 1024 + idx];
        }
        __syncthreads();

        // --- scores for this thread's 16 m's (m = u*4 + c) ---
        float s[16];
        #pragma unroll
        for (int u = 0; u < 16; ++u) {
            const float4* kr = (const float4*)(Klds + (u * 4 + c) * 64);
            float b0=0.f, b1=0.f, b2=0.f, b3=0.f;
            #pragma unroll
            for (int dq = 0; dq < 16; ++dq) {
                float4 kv = kr[dq];
                b0 = fmaf(q4[dq].x, kv.x, b0);
                b1 = fmaf(q4[dq].y, kv.y, b1);
                b2 = fmaf(q4[dq].z, kv.z, b2);
                b3 = fmaf(q4[dq].w, kv.w, b3);
            }
            s[u] = (b0 + b1) + (b2 + b3);     // q pre-scaled by 1/sqrt(K)
        }

        // --- online softmax update (one rescale per 64-m tile) ---
        float smax = s[0];
        #pragma unroll
        for (int u = 1; u < 16; ++u) smax = fmaxf(smax, s[u]);
        float mnew = fmaxf(mi, smax);
        float corr = __expf(mi - mnew);
        mi = mnew;
        float p[16], psum = 0.f;
        #pragma unroll
        for (int u = 0; u < 16; ++u) { p[u] = __expf(s[u] - mnew); psum += p[u]; }
        li = li * corr + psum;
        #pragma unroll
        for (int i = 0; i < 16; ++i) {
            o4[i].x *= corr; o4[i].y *= corr; o4[i].z *= corr; o4[i].w *= corr;
        }
        // --- PV accumulate ---
        #pragma unroll
        for (int jq = 0; jq < 16; ++jq) {
            float4 oa = o4[jq];
            #pragma unroll
            for (int u = 0; u < 16; ++u) {
                float4 vr = *(const float4*)(Vlds + (u * 4 + c) * 64 + jq * 4);
                oa.x = fmaf(p[u], vr.x, oa.x);
                oa.y = fmaf(p[u], vr.y, oa.y);
                oa.z = fmaf(p[u], vr.z, oa.z);
                oa.w = fmaf(p[u], vr.w, oa.w);
            }
            o4[jq] = oa;
        }
    }

    // --- merge 4 partial flash states per row ---
    __syncthreads();
    mred[c * 64 + row] = mi;
    lred[c * 64 + row] = li;
    __syncthreads();
    float M = mred[row];
    #pragma unroll
    for (int cc = 1; cc < 4; ++cc) M = fmaxf(M, mred[cc * 64 + row]);
    float L = 0.f;
    #pragma unroll
    for (int cc = 0; cc < 4; ++cc) L += lred[cc * 64 + row] * __expf(mred[cc * 64 + row] - M);
    float f = __expf(mi - M);
    if (c == 0) linv[row] = 1.0f / L;

    #pragma unroll
    for (int turn = 0; turn < 4; ++turn) {
        if (c == turn) {
            #pragma unroll
            for (int jq = 0; jq < 16; ++jq) {
                float* dst = &olds[row * 65 + jq * 4];
                if (turn == 0) {
                    dst[0] = f * o4[jq].x; dst[1] = f * o4[jq].y;
                    dst[2] = f * o4[jq].z; dst[3] = f * o4[jq].w;
                } else {
                    dst[0] += f * o4[jq].x; dst[1] += f * o4[jq].y;
                    dst[2] += f * o4[jq].z; dst[3] += f * o4[jq].w;
                }
            }
        }
        __syncthreads();
    }

    // --- write o[b][n][h][v], normalized; coalesced over j ---
    #pragma unroll
    for (int i = 0; i < 16; ++i) {
        int e = tid + i * 256;   // 0..4095 over (row, j)
        int jj = e & 63;
        int rr = e >> 6;
        o[(((size_t)b * NSEQ + n0 + rr) * NHEAD + h) * 64 + jj] =
            olds[rr * 65 + jj] * linv[rr];
    }
}

// ---------------------------------------------------------------------------
// Kernel 5: output projection.
// out[b][d][n] = sum_{hv} o[b][n][hv] * op[d][hv]   (hv = h*64+v, contiguous
// in both operands). Lane = n (coalesced store); 16-d register blocking.
// ---------------------------------------------------------------------------
__global__ __launch_bounds__(256) void out_proj_kernel(
    const float* __restrict__ o, const float* __restrict__ op, float* __restrict__ out)
{
    int tid = threadIdx.x;
    int lane = tid & 63;
    int dl = tid >> 6;
    int b = blockIdx.z;
    int d0 = blockIdx.y * 64 + dl * 16;
    int n = blockIdx.x * 64 + lane;
    const float4* orow = (const float4*)(o + ((size_t)b * NSEQ + n) * 512);
    float acc[16];
    #pragma unroll
    for (int r = 0; r < 16; ++r) acc[r] = 0.f;
    for (int hq = 0; hq < 128; ++hq) {
        float4 ov = orow[hq];
        #pragma unroll
        for (int r = 0; r < 16; ++r) {
            float4 w = *(const float4*)(op + (size_t)(d0 + r) * 512 + hq * 4);
            acc[r] = fmaf(ov.x, w.x, acc[r]);
            acc[r] = fmaf(ov.y, w.y, acc[r]);
            acc[r] = fmaf(ov.z, w.z, acc[r]);
            acc[r] = fmaf(ov.w, w.w, acc[r]);
        }
    }
    #pragma unroll
    for (int r = 0; r < 16; ++r)
        out[((size_t)b * DDIM + d0 + r) * NSEQ + n] = acc[r];
}

// ---------------------------------------------------------------------------
extern "C" void kernel_launch(void* const* d_in, const int* in_sizes, int n_in,
                              void* d_out, int out_size, void* d_ws, size_t ws_size,
                              hipStream_t stream) {
    const float* x  = (const float*)d_in[0];   // (2,512,2048)
    const float* qp = (const float*)d_in[1];   // (8,64,512)
    const float* kp = (const float*)d_in[2];   // (512,64)
    const float* vp = (const float*)d_in[3];   // (512,64)
    const float* op = (const float*)d_in[4];   // (512,8,64) == (512,512)
    float* out = (float*)d_out;                // (2,512,2048)

    // Workspace layout (floats); total 4,980,736 floats = 19.9 MB
    float* ws  = (float*)d_ws;
    float* kk  = ws;                 // B*N*64      = 262144
    float* vv  = kk + 262144;        // B*N*64      = 262144
    float* qpT = vv + 262144;        // H*512*64    = 262144
    float* q   = qpT + 262144;       // B*N*H*64    = 2097152
    float* o   = q + 2097152;        // B*N*H*64    = 2097152

    hipLaunchKernelGGL(kv_proj_kernel,    dim3(256),       dim3(256), 0, stream, x, kp, vp, kk, vv);
    hipLaunchKernelGGL(qp_transpose_kernel, dim3(1024),    dim3(256), 0, stream, qp, qpT);
    hipLaunchKernelGGL(q_proj_kernel,     dim3(2048),      dim3(256), 0, stream, x, qpT, q);
    hipLaunchKernelGGL(attn_kernel,       dim3(32, 8, 2),  dim3(256), 0, stream, q, kk, vv, o);
    hipLaunchKernelGGL(out_proj_kernel,   dim3(32, 8, 2),  dim3(256), 0, stream, o, op, out);
}

// Round 2
// 586.312 us; speedup vs baseline: 1.4517x; 1.4517x over previous
//
#include <hip/hip_runtime.h>
#include <math.h>

// Problem constants: B=2, D=512, N=M=2048, H=8, K=V=64
#define BB 2
#define DDIM 512
#define NSEQ 2048
#define NHEAD 8

typedef __attribute__((ext_vector_type(4))) short s16x4;
typedef __attribute__((ext_vector_type(8))) short s16x8;
typedef __attribute__((ext_vector_type(4))) float f32x4;

__device__ __forceinline__ unsigned short f2bf(float f) {
    unsigned u = __float_as_uint(f);
    u = (u + 0x7FFFu + ((u >> 16) & 1u)) >> 16;   // RNE
    return (unsigned short)u;
}
__device__ __forceinline__ float bf2f(unsigned short h) {
    return __uint_as_float(((unsigned)h) << 16);
}

__device__ __forceinline__ f32x4 mfma32(s16x8 a, s16x8 b, f32x4 c) {
    return __builtin_amdgcn_mfma_f32_16x16x32_bf16(a, b, c, 0, 0, 0);
}
// K=16 bf16 MFMA; fallback emulates via K=32 with zeroed upper half (A dup slots
// multiplied by B zeros contribute 0).
__device__ __forceinline__ f32x4 mfma16(s16x4 a, s16x4 b, f32x4 c) {
#if __has_builtin(__builtin_amdgcn_mfma_f32_16x16x16bf16_1k)
    return __builtin_amdgcn_mfma_f32_16x16x16bf16_1k(a, b, c, 0, 0, 0);
#else
    s16x8 a8 = { a[0], a[1], a[2], a[3], 0, 0, 0, 0 };
    s16x8 b8 = { b[0], b[1], b[2], b[3], 0, 0, 0, 0 };
    return __builtin_amdgcn_mfma_f32_16x16x32_bf16(a8, b8, c, 0, 0, 0);
#endif
}

// ---------------------------------------------------------------------------
// Kernel 1: K/V projection -> K hi/lo bf16 [b][m][d] (plain), V^T hi/lo bf16
// [b][v][m] (transposed in-block through LDS). Lanes = feature j (coalesced
// weight reads); each thread 4 consecutive m via wave-uniform float4 x load.
// ---------------------------------------------------------------------------
__global__ __launch_bounds__(256) void kv_proj_kernel(
    const float* __restrict__ x, const float* __restrict__ kp,
    const float* __restrict__ vp,
    unsigned short* __restrict__ kkhi, unsigned short* __restrict__ kklo,
    unsigned short* __restrict__ vthi, unsigned short* __restrict__ vtlo)
{
    __shared__ float vbuf[64 * 17];   // [v][16 m + pad]
    int tid = threadIdx.x;
    int j = tid & 63;
    int g = tid >> 6;
    int flat = blockIdx.x * 4 + g;        // over B*N/4 = 1024
    int b = flat >> 9;
    int m0 = (flat & 511) << 2;
    const float* xb = x + (size_t)b * DDIM * NSEQ;
    float aK[4] = {0.f,0.f,0.f,0.f}, aV[4] = {0.f,0.f,0.f,0.f};
    for (int d = 0; d < DDIM; ++d) {
        float4 xv = *(const float4*)(xb + (size_t)d * NSEQ + m0);
        float kw = kp[d * 64 + j];
        float vw = vp[d * 64 + j];
        aK[0] = fmaf(xv.x, kw, aK[0]); aV[0] = fmaf(xv.x, vw, aV[0]);
        aK[1] = fmaf(xv.y, kw, aK[1]); aV[1] = fmaf(xv.y, vw, aV[1]);
        aK[2] = fmaf(xv.z, kw, aK[2]); aV[2] = fmaf(xv.z, vw, aV[2]);
        aK[3] = fmaf(xv.w, kw, aK[3]); aV[3] = fmaf(xv.w, vw, aV[3]);
    }
    size_t base = ((size_t)b * NSEQ + m0) * 64 + j;
    #pragma unroll
    for (int i = 0; i < 4; ++i) {
        unsigned short hi = f2bf(aK[i]);
        kkhi[base + i * 64] = hi;
        kklo[base + i * 64] = f2bf(aK[i] - bf2f(hi));
        vbuf[j * 17 + g * 4 + i] = aV[i];
    }
    __syncthreads();
    // transpose write: thread -> (v = tid>>2, 4 m's)
    int v = tid >> 2, mq = tid & 3;
    int b2 = blockIdx.x >> 7;
    int mb = (blockIdx.x & 127) * 16 + mq * 4;
    size_t vb = ((size_t)b2 * 64 + v) * NSEQ + mb;
    ushort4 hv, lv;
    #pragma unroll
    for (int i2 = 0; i2 < 4; ++i2) {
        float vv_ = vbuf[v * 17 + mq * 4 + i2];
        unsigned short hi = f2bf(vv_);
        ((unsigned short*)&hv)[i2] = hi;
        ((unsigned short*)&lv)[i2] = f2bf(vv_ - bf2f(hi));
    }
    *(ushort4*)(vthi + vb) = hv;
    *(ushort4*)(vtlo + vb) = lv;
}

// ---------------------------------------------------------------------------
// Kernel 2: transpose query_proj (H,K,D) -> qpT (H,D,K), fp32.
// ---------------------------------------------------------------------------
__global__ __launch_bounds__(256) void qp_transpose_kernel(
    const float* __restrict__ qp, float* __restrict__ qpT)
{
    int g = blockIdx.x * 256 + threadIdx.x;   // H*512*64 = 262144
    int j = g & 63;
    int d = (g >> 6) & 511;
    int h = g >> 15;
    qpT[g] = qp[((size_t)(h * 64 + j)) * DDIM + d];
}

// ---------------------------------------------------------------------------
// Kernel 3: Q projection (1/sqrt(K) folded) -> q hi/lo bf16 [b][h][n][d].
// ---------------------------------------------------------------------------
__global__ __launch_bounds__(256) void q_proj_kernel(
    const float* __restrict__ x, const float* __restrict__ qpT,
    unsigned short* __restrict__ qhi, unsigned short* __restrict__ qlo)
{
    int tid = threadIdx.x;
    int j = tid & 63;
    int sub = tid >> 6;
    int flat = blockIdx.x * 4 + sub;      // over B*(N/4)*H = 8192
    int h = flat & 7;
    int n4 = (flat >> 3) & 511;
    int b = flat >> 12;
    int n0 = n4 * 4;
    const float* xb = x + (size_t)b * DDIM * NSEQ;
    const float* wgt = qpT + (size_t)h * DDIM * 64 + j;
    float a[4] = {0.f,0.f,0.f,0.f};
    for (int d = 0; d < DDIM; ++d) {
        float4 xv = *(const float4*)(xb + (size_t)d * NSEQ + n0);
        float wv = wgt[d * 64];
        a[0] = fmaf(xv.x, wv, a[0]);
        a[1] = fmaf(xv.y, wv, a[1]);
        a[2] = fmaf(xv.z, wv, a[2]);
        a[3] = fmaf(xv.w, wv, a[3]);
    }
    #pragma unroll
    for (int i = 0; i < 4; ++i) {
        float val = a[i] * 0.125f;   // 1/sqrt(64)
        size_t idx = (((size_t)b * NHEAD + h) * NSEQ + n0 + i) * 64 + j;
        unsigned short hi = f2bf(val);
        qhi[idx] = hi;
        qlo[idx] = f2bf(val - bf2f(hi));
    }
}

// ---------------------------------------------------------------------------
// Kernel 4: MFMA flash attention.
// Block = (b, h, 64 n-rows), 4 waves. Wave w owns m-subtile w (16 m's of each
// 64-m tile) for ALL 64 n -> computes S^T = K·Q^T (C-layout row = m), so P in
// registers IS the mfma_16x16x16 B-fragment for PV (O^T = V^T·P^T): no
// transpose. Q/K hi+lo bf16 3-pass; V hi+lo into same accumulator; P bf16.
// K and V^T tiles double-buffered in LDS via global_load_lds(16B) with XOR
// granule swizzle encoded in the GLOBAL source addresses (bank-even ds_reads).
// 4 per-wave partial flash states merged via LDS at end; o written bf16
// [b][n][h*64+v].
// ---------------------------------------------------------------------------
__global__ __launch_bounds__(256, 2) void attn_kernel(
    const unsigned short* __restrict__ kkhi, const unsigned short* __restrict__ kklo,
    const unsigned short* __restrict__ vthi, const unsigned short* __restrict__ vtlo,
    const unsigned short* __restrict__ qhi,  const unsigned short* __restrict__ qlo,
    unsigned short* __restrict__ obf)
{
    __shared__ __align__(128) char arena[65536];  // [2 bufs][Khi|Klo|VThi|VTlo] 8KB each

    const int tid = threadIdx.x;
    const int w  = tid >> 6;        // wave 0..3 = m-subtile owner
    const int l  = tid & 63;
    const int qd = l >> 4;          // quad
    const int ln = l & 15;
    const int bz = blockIdx.z, hz = blockIdx.y;
    const int n0 = blockIdx.x * 64;

    // ---- Q fragments, resident all kernel: B-frag = Q[n=ln][d=qd*8+j] ----
    s16x8 qh[4][2], qlo_[4][2];
    {
        size_t rowb = (((size_t)bz * NHEAD + hz) * NSEQ + n0 + ln) * 64 + qd * 8;
        #pragma unroll
        for (int t = 0; t < 4; ++t)
            #pragma unroll
            for (int c = 0; c < 2; ++c) {
                qh[t][c]   = *(const s16x8*)(qhi + rowb + (size_t)t * 16 * 64 + c * 32);
                qlo_[t][c] = *(const s16x8*)(qlo + rowb + (size_t)t * 16 * 64 + c * 32);
            }
    }

    // ---- staging: wave w stages array w (8 KB) of each tile, 8 instrs ----
    const int vrow = l >> 3;             // row-within-octet
    const int gsw  = (l & 7) ^ vrow;     // XOR granule swizzle (in global addr)
    const char* sb; int rs, ts;
    if      (w == 0) { sb = (const char*)kkhi; rs = 128;  ts = 8192; }
    else if (w == 1) { sb = (const char*)kklo; rs = 128;  ts = 8192; }
    else if (w == 2) { sb = (const char*)vthi; rs = 4096; ts = 128;  }
    else             { sb = (const char*)vtlo; rs = 4096; ts = 128;  }
    sb += (size_t)bz * 262144 + (size_t)vrow * rs + (size_t)gsw * 16;
    char* ldst0 = arena + w * 8192;

    auto stage = [&](int buf, int mt) {
        const char* gg = sb + (size_t)mt * ts;
        char* dst = ldst0 + buf * 32768;
        #pragma unroll
        for (int i = 0; i < 8; ++i) {
            __builtin_amdgcn_global_load_lds(
                (const __attribute__((address_space(1))) unsigned int*)(gg + (size_t)i * 8 * rs),
                (__attribute__((address_space(3))) unsigned int*)(dst + i * 1024),
                16, 0, 0);
        }
    };

    // LDS read byte-offsets (swizzle-matched)
    int offK[2], offV[4];
    #pragma unroll
    for (int c = 0; c < 2; ++c)
        offK[c] = (w * 16 + ln) * 128 + (((c * 4 + qd) ^ (ln & 7)) * 16);
    #pragma unroll
    for (int s = 0; s < 4; ++s)
        offV[s] = (s * 16 + ln) * 128 + (((2 * w + (qd >> 1)) ^ (ln & 7)) * 16) + (qd & 1) * 8;

    f32x4 O[4][4];   // [v-subtile][n-subtile], C-layout col=n row=v
    const f32x4 vzero = {0.f, 0.f, 0.f, 0.f};
    #pragma unroll
    for (int s = 0; s < 4; ++s)
        #pragma unroll
        for (int t = 0; t < 4; ++t) O[s][t] = vzero;
    float mi[4], li[4];
    #pragma unroll
    for (int t = 0; t < 4; ++t) { mi[t] = -1e30f; li[t] = 0.f; }

    stage(0, 0);

    for (int mt = 0; mt < 32; ++mt) {
        int buf = mt & 1;
        __syncthreads();                       // drains this tile's loads
        if (mt + 1 < 32) stage(buf ^ 1, mt + 1);  // prefetch overlaps compute
        const char* Kh = arena + buf * 32768;
        const char* Kl = Kh + 8192;
        const char* Vh = Kh + 16384;
        const char* Vl = Kh + 24576;

        s16x8 kh[2], kl[2];
        #pragma unroll
        for (int c = 0; c < 2; ++c) {
            kh[c] = *(const s16x8*)(Kh + offK[c]);
            kl[c] = *(const s16x8*)(Kl + offK[c]);
        }
        // S^T = K·Q^T, 3-pass split: kh·qh + kh·ql + kl·qh
        f32x4 S[4];
        #pragma unroll
        for (int t = 0; t < 4; ++t) S[t] = vzero;
        #pragma unroll
        for (int c = 0; c < 2; ++c)
            #pragma unroll
            for (int t = 0; t < 4; ++t) {
                S[t] = mfma32(kh[c], qh[t][c],   S[t]);
                S[t] = mfma32(kh[c], qlo_[t][c], S[t]);
                S[t] = mfma32(kl[c], qh[t][c],   S[t]);
            }

        // online softmax over this wave's 16 m's (in-lane 4 + cross-quad)
        s16x4 pb[4]; float corr[4];
        #pragma unroll
        for (int t = 0; t < 4; ++t) {
            float rmax = fmaxf(fmaxf(S[t][0], S[t][1]), fmaxf(S[t][2], S[t][3]));
            rmax = fmaxf(rmax, __shfl_xor(rmax, 16, 64));
            rmax = fmaxf(rmax, __shfl_xor(rmax, 32, 64));
            float mnew = fmaxf(mi[t], rmax);
            corr[t] = __expf(mi[t] - mnew);
            mi[t] = mnew;
            float p0 = __expf(S[t][0] - mnew);
            float p1 = __expf(S[t][1] - mnew);
            float p2 = __expf(S[t][2] - mnew);
            float p3 = __expf(S[t][3] - mnew);
            float ps = p0 + p1 + p2 + p3;
            ps += __shfl_xor(ps, 16, 64);
            ps += __shfl_xor(ps, 32, 64);
            li[t] = li[t] * corr[t] + ps;
            s16x4 pv;
            pv[0] = (short)f2bf(p0); pv[1] = (short)f2bf(p1);
            pv[2] = (short)f2bf(p2); pv[3] = (short)f2bf(p3);
            pb[t] = pv;   // == B-frag of mfma16: k = qd*4 + j  (no transpose!)
        }
        #pragma unroll
        for (int s = 0; s < 4; ++s)
            #pragma unroll
            for (int t = 0; t < 4; ++t)
                O[s][t] *= corr[t];
        // O^T += V^T·P^T (hi and lo V into same accumulator)
        #pragma unroll
        for (int s = 0; s < 4; ++s) {
            s16x4 vh = *(const s16x4*)(Vh + offV[s]);
            s16x4 vl = *(const s16x4*)(Vl + offV[s]);
            #pragma unroll
            for (int t = 0; t < 4; ++t) {
                O[s][t] = mfma16(vh, pb[t], O[s][t]);
                O[s][t] = mfma16(vl, pb[t], O[s][t]);
            }
        }
    }

    // ---- merge 4 per-wave partial states (reuses buf0 LDS region) ----
    float* obuf  = (float*)arena;                 // [64 v][17] one n-subtile
    float* mlm   = (float*)(arena + 4608);        // [4 w][64 n]
    float* mll   = (float*)(arena + 5632);
    float* linvs = (float*)(arena + 6656);        // [64 n]

    if (qd == 0) {
        #pragma unroll
        for (int t = 0; t < 4; ++t) {
            mlm[w * 64 + t * 16 + ln] = mi[t];
            mll[w * 64 + t * 16 + ln] = li[t];
        }
    }
    __syncthreads();
    float f[4];
    #pragma unroll
    for (int t = 0; t < 4; ++t) {
        float M = mlm[t * 16 + ln];
        M = fmaxf(M, mlm[64 + t * 16 + ln]);
        M = fmaxf(M, mlm[128 + t * 16 + ln]);
        M = fmaxf(M, mlm[192 + t * 16 + ln]);
        float L = 0.f;
        #pragma unroll
        for (int ww = 0; ww < 4; ++ww)
            L += mll[ww * 64 + t * 16 + ln] * __expf(mlm[ww * 64 + t * 16 + ln] - M);
        f[t] = __expf(mi[t] - M);
        if (w == 0 && qd == 0) linvs[t * 16 + ln] = 1.0f / L;
    }

    #pragma unroll
    for (int t = 0; t < 4; ++t) {
        #pragma unroll
        for (int r = 0; r < 4; ++r) {
            __syncthreads();
            int s = (w + r) & 3;                  // staggered regions, no overlap
            f32x4 val = O[s][t] * f[t];
            float* dst = obuf + (s * 16 + qd * 4) * 17 + ln;
            if (r == 0) {
                dst[0] = val[0]; dst[17] = val[1]; dst[34] = val[2]; dst[51] = val[3];
            } else {
                dst[0] += val[0]; dst[17] += val[1]; dst[34] += val[2]; dst[51] += val[3];
            }
        }
        __syncthreads();
        // write o[b][n][h*64+v] bf16, n = n0 + t*16 + nl; 16 lanes/v-row contig
        int vq = tid & 15, nl = tid >> 4;
        float il = linvs[t * 16 + nl];
        ushort4 u4;
        u4.x = f2bf(obuf[(vq * 4 + 0) * 17 + nl] * il);
        u4.y = f2bf(obuf[(vq * 4 + 1) * 17 + nl] * il);
        u4.z = f2bf(obuf[(vq * 4 + 2) * 17 + nl] * il);
        u4.w = f2bf(obuf[(vq * 4 + 3) * 17 + nl] * il);
        *(ushort4*)(obf + (((size_t)bz * NSEQ + n0 + t * 16 + nl) * 512) + hz * 64 + vq * 4) = u4;
    }
}

// ---------------------------------------------------------------------------
// Kernel 5: output projection (fp32 math, bf16 o input).
// out[b][d][n] = sum_{hv} o[b][n][hv] * op[d][hv]
// ---------------------------------------------------------------------------
__global__ __launch_bounds__(256) void out_proj_kernel(
    const unsigned short* __restrict__ obf, const float* __restrict__ op,
    float* __restrict__ out)
{
    int tid = threadIdx.x;
    int lane = tid & 63;
    int dl = tid >> 6;
    int b = blockIdx.z;
    int d0 = blockIdx.y * 64 + dl * 16;
    int n = blockIdx.x * 64 + lane;
    const unsigned short* orow = obf + ((size_t)b * NSEQ + n) * 512;
    float acc[16];
    #pragma unroll
    for (int r = 0; r < 16; ++r) acc[r] = 0.f;
    for (int hq = 0; hq < 128; ++hq) {
        ushort4 t4 = *(const ushort4*)(orow + hq * 4);
        float4 ov = make_float4(bf2f(t4.x), bf2f(t4.y), bf2f(t4.z), bf2f(t4.w));
        #pragma unroll
        for (int r = 0; r < 16; ++r) {
            float4 wv = *(const float4*)(op + (size_t)(d0 + r) * 512 + hq * 4);
            acc[r] = fmaf(ov.x, wv.x, acc[r]);
            acc[r] = fmaf(ov.y, wv.y, acc[r]);
            acc[r] = fmaf(ov.z, wv.z, acc[r]);
            acc[r] = fmaf(ov.w, wv.w, acc[r]);
        }
    }
    #pragma unroll
    for (int r = 0; r < 16; ++r)
        out[((size_t)b * DDIM + d0 + r) * NSEQ + n] = acc[r];
}

// ---------------------------------------------------------------------------
extern "C" void kernel_launch(void* const* d_in, const int* in_sizes, int n_in,
                              void* d_out, int out_size, void* d_ws, size_t ws_size,
                              hipStream_t stream) {
    const float* x  = (const float*)d_in[0];   // (2,512,2048)
    const float* qp = (const float*)d_in[1];   // (8,64,512)
    const float* kp = (const float*)d_in[2];   // (512,64)
    const float* vp = (const float*)d_in[3];   // (512,64)
    const float* op = (const float*)d_in[4];   // (512,8,64)
    float* out = (float*)d_out;                // (2,512,2048)

    // Workspace (15 MB total):
    unsigned short* kkhi = (unsigned short*)d_ws;      // 262144 bf16
    unsigned short* kklo = kkhi + 262144;
    unsigned short* vthi = kklo + 262144;              // V^T [b][v][m]
    unsigned short* vtlo = vthi + 262144;
    float*          qpT  = (float*)(vtlo + 262144);    // 262144 fp32
    unsigned short* qhi  = (unsigned short*)(qpT + 262144);  // 2097152 bf16
    unsigned short* qlo  = qhi + 2097152;
    unsigned short* obf  = qlo + 2097152;              // 2097152 bf16

    hipLaunchKernelGGL(kv_proj_kernel,      dim3(256),      dim3(256), 0, stream,
                       x, kp, vp, kkhi, kklo, vthi, vtlo);
    hipLaunchKernelGGL(qp_transpose_kernel, dim3(1024),     dim3(256), 0, stream, qp, qpT);
    hipLaunchKernelGGL(q_proj_kernel,       dim3(2048),     dim3(256), 0, stream,
                       x, qpT, qhi, qlo);
    hipLaunchKernelGGL(attn_kernel,         dim3(32, 8, 2), dim3(256), 0, stream,
                       kkhi, kklo, vthi, vtlo, qhi, qlo, obf);
    hipLaunchKernelGGL(out_proj_kernel,     dim3(32, 8, 2), dim3(256), 0, stream,
                       obf, op, out);
}

// Round 3
// 475.750 us; speedup vs baseline: 1.7890x; 1.2324x over previous
//
#include <hip/hip_runtime.h>
#include <math.h>

// Problem constants: B=2, D=512, N=M=2048, H=8, K=V=64
#define BB 2
#define DDIM 512
#define NSEQ 2048
#define NHEAD 8

typedef __attribute__((ext_vector_type(4))) short s16x4;
typedef __attribute__((ext_vector_type(8))) short s16x8;
typedef __attribute__((ext_vector_type(4))) float f32x4;

__device__ __forceinline__ unsigned short f2bf(float f) {
    unsigned u = __float_as_uint(f);
    u = (u + 0x7FFFu + ((u >> 16) & 1u)) >> 16;   // RNE
    return (unsigned short)u;
}
__device__ __forceinline__ float bf2f(unsigned short h) {
    return __uint_as_float(((unsigned)h) << 16);
}

__device__ __forceinline__ f32x4 mfma32(s16x8 a, s16x8 b, f32x4 c) {
    return __builtin_amdgcn_mfma_f32_16x16x32_bf16(a, b, c, 0, 0, 0);
}
// K=16 bf16 MFMA; fallback emulates via K=32 with zeroed upper half.
__device__ __forceinline__ f32x4 mfma16(s16x4 a, s16x4 b, f32x4 c) {
#if __has_builtin(__builtin_amdgcn_mfma_f32_16x16x16bf16_1k)
    return __builtin_amdgcn_mfma_f32_16x16x16bf16_1k(a, b, c, 0, 0, 0);
#else
    s16x8 a8 = { a[0], a[1], a[2], a[3], 0, 0, 0, 0 };
    s16x8 b8 = { b[0], b[1], b[2], b[3], 0, 0, 0, 0 };
    return __builtin_amdgcn_mfma_f32_16x16x32_bf16(a8, b8, c, 0, 0, 0);
#endif
}

// ---------------------------------------------------------------------------
// Kernel 1: K/V projection -> K hi/lo bf16 [b][m][d], V^T hi/lo bf16 [b][v][m].
// ---------------------------------------------------------------------------
__global__ __launch_bounds__(256) void kv_proj_kernel(
    const float* __restrict__ x, const float* __restrict__ kp,
    const float* __restrict__ vp,
    unsigned short* __restrict__ kkhi, unsigned short* __restrict__ kklo,
    unsigned short* __restrict__ vthi, unsigned short* __restrict__ vtlo)
{
    __shared__ float vbuf[64 * 17];   // [v][16 m + pad]
    int tid = threadIdx.x;
    int j = tid & 63;
    int g = tid >> 6;
    int flat = blockIdx.x * 4 + g;        // over B*N/4 = 1024
    int b = flat >> 9;
    int m0 = (flat & 511) << 2;
    const float* xb = x + (size_t)b * DDIM * NSEQ;
    float aK[4] = {0.f,0.f,0.f,0.f}, aV[4] = {0.f,0.f,0.f,0.f};
    for (int d = 0; d < DDIM; ++d) {
        float4 xv = *(const float4*)(xb + (size_t)d * NSEQ + m0);
        float kw = kp[d * 64 + j];
        float vw = vp[d * 64 + j];
        aK[0] = fmaf(xv.x, kw, aK[0]); aV[0] = fmaf(xv.x, vw, aV[0]);
        aK[1] = fmaf(xv.y, kw, aK[1]); aV[1] = fmaf(xv.y, vw, aV[1]);
        aK[2] = fmaf(xv.z, kw, aK[2]); aV[2] = fmaf(xv.z, vw, aV[2]);
        aK[3] = fmaf(xv.w, kw, aK[3]); aV[3] = fmaf(xv.w, vw, aV[3]);
    }
    size_t base = ((size_t)b * NSEQ + m0) * 64 + j;
    #pragma unroll
    for (int i = 0; i < 4; ++i) {
        unsigned short hi = f2bf(aK[i]);
        kkhi[base + i * 64] = hi;
        kklo[base + i * 64] = f2bf(aK[i] - bf2f(hi));
        vbuf[j * 17 + g * 4 + i] = aV[i];
    }
    __syncthreads();
    int v = tid >> 2, mq = tid & 3;
    int b2 = blockIdx.x >> 7;
    int mb = (blockIdx.x & 127) * 16 + mq * 4;
    size_t vb = ((size_t)b2 * 64 + v) * NSEQ + mb;
    ushort4 hv, lv;
    #pragma unroll
    for (int i2 = 0; i2 < 4; ++i2) {
        float vv_ = vbuf[v * 17 + mq * 4 + i2];
        unsigned short hi = f2bf(vv_);
        ((unsigned short*)&hv)[i2] = hi;
        ((unsigned short*)&lv)[i2] = f2bf(vv_ - bf2f(hi));
    }
    *(ushort4*)(vthi + vb) = hv;
    *(ushort4*)(vtlo + vb) = lv;
}

// ---------------------------------------------------------------------------
// Kernel 2: transpose query_proj (H,K,D) -> qpT (H,D,K), fp32.
// ---------------------------------------------------------------------------
__global__ __launch_bounds__(256) void qp_transpose_kernel(
    const float* __restrict__ qp, float* __restrict__ qpT)
{
    int g = blockIdx.x * 256 + threadIdx.x;   // H*512*64 = 262144
    int j = g & 63;
    int d = (g >> 6) & 511;
    int h = g >> 15;
    qpT[g] = qp[((size_t)(h * 64 + j)) * DDIM + d];
}

// ---------------------------------------------------------------------------
// Kernel 3: Q projection (1/sqrt(K) folded) -> q hi/lo bf16 [b][h][n][d].
// Each thread now owns 8 consecutive n: 2 float4 x-loads share one weight
// load -> halves weight traffic per FLOP vs round 2.
// ---------------------------------------------------------------------------
__global__ __launch_bounds__(256) void q_proj_kernel(
    const float* __restrict__ x, const float* __restrict__ qpT,
    unsigned short* __restrict__ qhi, unsigned short* __restrict__ qlo)
{
    int tid = threadIdx.x;
    int j = tid & 63;
    int sub = tid >> 6;
    int flat = blockIdx.x * 4 + sub;      // over B*(N/8)*H = 4096
    int h = flat & 7;
    int n8 = (flat >> 3) & 255;
    int b = flat >> 11;
    int n0 = n8 * 8;
    const float* xb = x + (size_t)b * DDIM * NSEQ;
    const float* wgt = qpT + (size_t)h * DDIM * 64 + j;
    float a[8] = {0.f,0.f,0.f,0.f,0.f,0.f,0.f,0.f};
    for (int d = 0; d < DDIM; ++d) {
        float4 x0 = *(const float4*)(xb + (size_t)d * NSEQ + n0);
        float4 x1 = *(const float4*)(xb + (size_t)d * NSEQ + n0 + 4);
        float wv = wgt[d * 64];
        a[0] = fmaf(x0.x, wv, a[0]);
        a[1] = fmaf(x0.y, wv, a[1]);
        a[2] = fmaf(x0.z, wv, a[2]);
        a[3] = fmaf(x0.w, wv, a[3]);
        a[4] = fmaf(x1.x, wv, a[4]);
        a[5] = fmaf(x1.y, wv, a[5]);
        a[6] = fmaf(x1.z, wv, a[6]);
        a[7] = fmaf(x1.w, wv, a[7]);
    }
    #pragma unroll
    for (int i = 0; i < 8; ++i) {
        float val = a[i] * 0.125f;   // 1/sqrt(64)
        size_t idx = (((size_t)b * NHEAD + h) * NSEQ + n0 + i) * 64 + j;
        unsigned short hi = f2bf(val);
        qhi[idx] = hi;
        qlo[idx] = f2bf(val - bf2f(hi));
    }
}

// ---------------------------------------------------------------------------
// Kernel 4: MFMA flash attention (see round-2 comments).
// FIX vs round 2: the epilogue merge previously indexed O[s][t] with a
// RUNTIME s = (w+r)&3, forcing O[4][4] into scratch for the whole kernel
// (866 MB of HBM scratch writes/dispatch). Now s is a compile-time unroll
// with a wave-uniform predicate -> O stays in registers.
// ---------------------------------------------------------------------------
__global__ __launch_bounds__(256, 2) void attn_kernel(
    const unsigned short* __restrict__ kkhi, const unsigned short* __restrict__ kklo,
    const unsigned short* __restrict__ vthi, const unsigned short* __restrict__ vtlo,
    const unsigned short* __restrict__ qhi,  const unsigned short* __restrict__ qlo,
    unsigned short* __restrict__ obf)
{
    __shared__ __align__(128) char arena[65536];  // [2 bufs][Khi|Klo|VThi|VTlo] 8KB each

    const int tid = threadIdx.x;
    const int w  = tid >> 6;        // wave 0..3 = m-subtile owner
    const int l  = tid & 63;
    const int qd = l >> 4;          // quad
    const int ln = l & 15;
    const int bz = blockIdx.z, hz = blockIdx.y;
    const int n0 = blockIdx.x * 64;

    // ---- Q fragments, resident all kernel: B-frag = Q[n=ln][d=qd*8+j] ----
    s16x8 qh[4][2], qlo_[4][2];
    {
        size_t rowb = (((size_t)bz * NHEAD + hz) * NSEQ + n0 + ln) * 64 + qd * 8;
        #pragma unroll
        for (int t = 0; t < 4; ++t)
            #pragma unroll
            for (int c = 0; c < 2; ++c) {
                qh[t][c]   = *(const s16x8*)(qhi + rowb + (size_t)t * 16 * 64 + c * 32);
                qlo_[t][c] = *(const s16x8*)(qlo + rowb + (size_t)t * 16 * 64 + c * 32);
            }
    }

    // ---- staging: wave w stages array w (8 KB) of each tile, 8 instrs ----
    const int vrow = l >> 3;             // row-within-octet
    const int gsw  = (l & 7) ^ vrow;     // XOR granule swizzle (in global addr)
    const char* sb; int rs, ts;
    if      (w == 0) { sb = (const char*)kkhi; rs = 128;  ts = 8192; }
    else if (w == 1) { sb = (const char*)kklo; rs = 128;  ts = 8192; }
    else if (w == 2) { sb = (const char*)vthi; rs = 4096; ts = 128;  }
    else             { sb = (const char*)vtlo; rs = 4096; ts = 128;  }
    sb += (size_t)bz * 262144 + (size_t)vrow * rs + (size_t)gsw * 16;
    char* ldst0 = arena + w * 8192;

    auto stage = [&](int buf, int mt) {
        const char* gg = sb + (size_t)mt * ts;
        char* dst = ldst0 + buf * 32768;
        #pragma unroll
        for (int i = 0; i < 8; ++i) {
            __builtin_amdgcn_global_load_lds(
                (const __attribute__((address_space(1))) unsigned int*)(gg + (size_t)i * 8 * rs),
                (__attribute__((address_space(3))) unsigned int*)(dst + i * 1024),
                16, 0, 0);
        }
    };

    // LDS read byte-offsets (swizzle-matched)
    int offK[2], offV[4];
    #pragma unroll
    for (int c = 0; c < 2; ++c)
        offK[c] = (w * 16 + ln) * 128 + (((c * 4 + qd) ^ (ln & 7)) * 16);
    #pragma unroll
    for (int s = 0; s < 4; ++s)
        offV[s] = (s * 16 + ln) * 128 + (((2 * w + (qd >> 1)) ^ (ln & 7)) * 16) + (qd & 1) * 8;

    f32x4 O[4][4];   // [v-subtile][n-subtile], C-layout col=n row=v
    const f32x4 vzero = {0.f, 0.f, 0.f, 0.f};
    #pragma unroll
    for (int s = 0; s < 4; ++s)
        #pragma unroll
        for (int t = 0; t < 4; ++t) O[s][t] = vzero;
    float mi[4], li[4];
    #pragma unroll
    for (int t = 0; t < 4; ++t) { mi[t] = -1e30f; li[t] = 0.f; }

    stage(0, 0);

    for (int mt = 0; mt < 32; ++mt) {
        int buf = mt & 1;
        __syncthreads();                       // drains this tile's loads
        if (mt + 1 < 32) stage(buf ^ 1, mt + 1);  // prefetch overlaps compute
        const char* Kh = arena + buf * 32768;
        const char* Kl = Kh + 8192;
        const char* Vh = Kh + 16384;
        const char* Vl = Kh + 24576;

        s16x8 kh[2], kl[2];
        #pragma unroll
        for (int c = 0; c < 2; ++c) {
            kh[c] = *(const s16x8*)(Kh + offK[c]);
            kl[c] = *(const s16x8*)(Kl + offK[c]);
        }
        // S^T = K·Q^T, 3-pass split: kh·qh + kh·ql + kl·qh
        f32x4 S[4];
        #pragma unroll
        for (int t = 0; t < 4; ++t) S[t] = vzero;
        #pragma unroll
        for (int c = 0; c < 2; ++c)
            #pragma unroll
            for (int t = 0; t < 4; ++t) {
                S[t] = mfma32(kh[c], qh[t][c],   S[t]);
                S[t] = mfma32(kh[c], qlo_[t][c], S[t]);
                S[t] = mfma32(kl[c], qh[t][c],   S[t]);
            }

        // online softmax over this wave's 16 m's
        s16x4 pb[4]; float corr[4];
        #pragma unroll
        for (int t = 0; t < 4; ++t) {
            float rmax = fmaxf(fmaxf(S[t][0], S[t][1]), fmaxf(S[t][2], S[t][3]));
            rmax = fmaxf(rmax, __shfl_xor(rmax, 16, 64));
            rmax = fmaxf(rmax, __shfl_xor(rmax, 32, 64));
            float mnew = fmaxf(mi[t], rmax);
            corr[t] = __expf(mi[t] - mnew);
            mi[t] = mnew;
            float p0 = __expf(S[t][0] - mnew);
            float p1 = __expf(S[t][1] - mnew);
            float p2 = __expf(S[t][2] - mnew);
            float p3 = __expf(S[t][3] - mnew);
            float ps = p0 + p1 + p2 + p3;
            ps += __shfl_xor(ps, 16, 64);
            ps += __shfl_xor(ps, 32, 64);
            li[t] = li[t] * corr[t] + ps;
            s16x4 pv;
            pv[0] = (short)f2bf(p0); pv[1] = (short)f2bf(p1);
            pv[2] = (short)f2bf(p2); pv[3] = (short)f2bf(p3);
            pb[t] = pv;   // == B-frag of mfma16: k = qd*4 + j (no transpose)
        }
        #pragma unroll
        for (int s = 0; s < 4; ++s)
            #pragma unroll
            for (int t = 0; t < 4; ++t)
                O[s][t] *= corr[t];
        // O^T += V^T·P^T (hi and lo V into same accumulator)
        #pragma unroll
        for (int s = 0; s < 4; ++s) {
            s16x4 vh = *(const s16x4*)(Vh + offV[s]);
            s16x4 vl = *(const s16x4*)(Vl + offV[s]);
            #pragma unroll
            for (int t = 0; t < 4; ++t) {
                O[s][t] = mfma16(vh, pb[t], O[s][t]);
                O[s][t] = mfma16(vl, pb[t], O[s][t]);
            }
        }
    }

    // ---- merge 4 per-wave partial states (reuses buf0 LDS region) ----
    float* obuf  = (float*)arena;                 // [64 v][17] one n-subtile
    float* mlm   = (float*)(arena + 4608);        // [4 w][64 n]
    float* mll   = (float*)(arena + 5632);
    float* linvs = (float*)(arena + 6656);        // [64 n]

    if (qd == 0) {
        #pragma unroll
        for (int t = 0; t < 4; ++t) {
            mlm[w * 64 + t * 16 + ln] = mi[t];
            mll[w * 64 + t * 16 + ln] = li[t];
        }
    }
    __syncthreads();
    float f[4];
    #pragma unroll
    for (int t = 0; t < 4; ++t) {
        float M = mlm[t * 16 + ln];
        M = fmaxf(M, mlm[64 + t * 16 + ln]);
        M = fmaxf(M, mlm[128 + t * 16 + ln]);
        M = fmaxf(M, mlm[192 + t * 16 + ln]);
        float L = 0.f;
        #pragma unroll
        for (int ww = 0; ww < 4; ++ww)
            L += mll[ww * 64 + t * 16 + ln] * __expf(mlm[ww * 64 + t * 16 + ln] - M);
        f[t] = __expf(mi[t] - M);
        if (w == 0 && qd == 0) linvs[t * 16 + ln] = 1.0f / L;
    }

    #pragma unroll
    for (int t = 0; t < 4; ++t) {
        #pragma unroll
        for (int r = 0; r < 4; ++r) {
            __syncthreads();
            // COMPILE-TIME s; wave-uniform predicate picks the active wave.
            #pragma unroll
            for (int s = 0; s < 4; ++s) {
                if (((w + r) & 3) == s) {
                    f32x4 val = O[s][t] * f[t];
                    float* dst = obuf + (s * 16 + qd * 4) * 17 + ln;
                    if (r == 0) {
                        dst[0]  = val[0]; dst[17] = val[1];
                        dst[34] = val[2]; dst[51] = val[3];
                    } else {
                        dst[0]  += val[0]; dst[17] += val[1];
                        dst[34] += val[2]; dst[51] += val[3];
                    }
                }
            }
        }
        __syncthreads();
        // write o[b][n][h*64+v] bf16, n = n0 + t*16 + nl
        int vq = tid & 15, nl = tid >> 4;
        float il = linvs[t * 16 + nl];
        ushort4 u4;
        u4.x = f2bf(obuf[(vq * 4 + 0) * 17 + nl] * il);
        u4.y = f2bf(obuf[(vq * 4 + 1) * 17 + nl] * il);
        u4.z = f2bf(obuf[(vq * 4 + 2) * 17 + nl] * il);
        u4.w = f2bf(obuf[(vq * 4 + 3) * 17 + nl] * il);
        *(ushort4*)(obf + (((size_t)bz * NSEQ + n0 + t * 16 + nl) * 512) + hz * 64 + vq * 4) = u4;
    }
}

// ---------------------------------------------------------------------------
// Kernel 5: output projection (fp32 math, bf16 o input).
// ---------------------------------------------------------------------------
__global__ __launch_bounds__(256) void out_proj_kernel(
    const unsigned short* __restrict__ obf, const float* __restrict__ op,
    float* __restrict__ out)
{
    int tid = threadIdx.x;
    int lane = tid & 63;
    int dl = tid >> 6;
    int b = blockIdx.z;
    int d0 = blockIdx.y * 64 + dl * 16;
    int n = blockIdx.x * 64 + lane;
    const unsigned short* orow = obf + ((size_t)b * NSEQ + n) * 512;
    float acc[16];
    #pragma unroll
    for (int r = 0; r < 16; ++r) acc[r] = 0.f;
    for (int hq = 0; hq < 128; ++hq) {
        ushort4 t4 = *(const ushort4*)(orow + hq * 4);
        float4 ov = make_float4(bf2f(t4.x), bf2f(t4.y), bf2f(t4.z), bf2f(t4.w));
        #pragma unroll
        for (int r = 0; r < 16; ++r) {
            float4 wv = *(const float4*)(op + (size_t)(d0 + r) * 512 + hq * 4);
            acc[r] = fmaf(ov.x, wv.x, acc[r]);
            acc[r] = fmaf(ov.y, wv.y, acc[r]);
            acc[r] = fmaf(ov.z, wv.z, acc[r]);
            acc[r] = fmaf(ov.w, wv.w, acc[r]);
        }
    }
    #pragma unroll
    for (int r = 0; r < 16; ++r)
        out[((size_t)b * DDIM + d0 + r) * NSEQ + n] = acc[r];
}

// ---------------------------------------------------------------------------
extern "C" void kernel_launch(void* const* d_in, const int* in_sizes, int n_in,
                              void* d_out, int out_size, void* d_ws, size_t ws_size,
                              hipStream_t stream) {
    const float* x  = (const float*)d_in[0];   // (2,512,2048)
    const float* qp = (const float*)d_in[1];   // (8,64,512)
    const float* kp = (const float*)d_in[2];   // (512,64)
    const float* vp = (const float*)d_in[3];   // (512,64)
    const float* op = (const float*)d_in[4];   // (512,8,64)
    float* out = (float*)d_out;                // (2,512,2048)

    unsigned short* kkhi = (unsigned short*)d_ws;      // 262144 bf16
    unsigned short* kklo = kkhi + 262144;
    unsigned short* vthi = kklo + 262144;              // V^T [b][v][m]
    unsigned short* vtlo = vthi + 262144;
    float*          qpT  = (float*)(vtlo + 262144);    // 262144 fp32
    unsigned short* qhi  = (unsigned short*)(qpT + 262144);  // 2097152 bf16
    unsigned short* qlo  = qhi + 2097152;
    unsigned short* obf  = qlo + 2097152;              // 2097152 bf16

    hipLaunchKernelGGL(kv_proj_kernel,      dim3(256),      dim3(256), 0, stream,
                       x, kp, vp, kkhi, kklo, vthi, vtlo);
    hipLaunchKernelGGL(qp_transpose_kernel, dim3(1024),     dim3(256), 0, stream, qp, qpT);
    hipLaunchKernelGGL(q_proj_kernel,       dim3(1024),     dim3(256), 0, stream,
                       x, qpT, qhi, qlo);
    hipLaunchKernelGGL(attn_kernel,         dim3(32, 8, 2), dim3(256), 0, stream,
                       kkhi, kklo, vthi, vtlo, qhi, qlo, obf);
    hipLaunchKernelGGL(out_proj_kernel,     dim3(32, 8, 2), dim3(256), 0, stream,
                       obf, op, out);
}

// Round 4
// 225.493 us; speedup vs baseline: 3.7745x; 2.1098x over previous
//
#include <hip/hip_runtime.h>
#include <math.h>

// Problem constants: B=2, D=512, N=M=2048, H=8, K=V=64
#define BB 2
#define DDIM 512
#define NSEQ 2048
#define NHEAD 8

typedef __attribute__((ext_vector_type(4))) short s16x4;
typedef __attribute__((ext_vector_type(8))) short s16x8;
typedef __attribute__((ext_vector_type(4))) float f32x4;

__device__ __forceinline__ unsigned short f2bf(float f) {
    unsigned u = __float_as_uint(f);
    u = (u + 0x7FFFu + ((u >> 16) & 1u)) >> 16;   // RNE
    return (unsigned short)u;
}
__device__ __forceinline__ float bf2f(unsigned short h) {
    return __uint_as_float(((unsigned)h) << 16);
}

__device__ __forceinline__ f32x4 mfma32(s16x8 a, s16x8 b, f32x4 c) {
    return __builtin_amdgcn_mfma_f32_16x16x32_bf16(a, b, c, 0, 0, 0);
}
__device__ __forceinline__ f32x4 mfma16(s16x4 a, s16x4 b, f32x4 c) {
#if __has_builtin(__builtin_amdgcn_mfma_f32_16x16x16bf16_1k)
    return __builtin_amdgcn_mfma_f32_16x16x16bf16_1k(a, b, c, 0, 0, 0);
#else
    s16x8 a8 = { a[0], a[1], a[2], a[3], 0, 0, 0, 0 };
    s16x8 b8 = { b[0], b[1], b[2], b[3], 0, 0, 0, 0 };
    return __builtin_amdgcn_mfma_f32_16x16x32_bf16(a8, b8, c, 0, 0, 0);
#endif
}

// ---------------------------------------------------------------------------
// Kernel 1: K/V projection (fp32 vector) -> K hi/lo bf16 [b][m][d],
// V^T hi/lo bf16 [b][v][m]. Unchanged from round 3.
// ---------------------------------------------------------------------------
__global__ __launch_bounds__(256) void kv_proj_kernel(
    const float* __restrict__ x, const float* __restrict__ kp,
    const float* __restrict__ vp,
    unsigned short* __restrict__ kkhi, unsigned short* __restrict__ kklo,
    unsigned short* __restrict__ vthi, unsigned short* __restrict__ vtlo)
{
    __shared__ float vbuf[64 * 17];   // [v][16 m + pad]
    int tid = threadIdx.x;
    int j = tid & 63;
    int g = tid >> 6;
    int flat = blockIdx.x * 4 + g;        // over B*N/4 = 1024
    int b = flat >> 9;
    int m0 = (flat & 511) << 2;
    const float* xb = x + (size_t)b * DDIM * NSEQ;
    float aK[4] = {0.f,0.f,0.f,0.f}, aV[4] = {0.f,0.f,0.f,0.f};
    for (int d = 0; d < DDIM; ++d) {
        float4 xv = *(const float4*)(xb + (size_t)d * NSEQ + m0);
        float kw = kp[d * 64 + j];
        float vw = vp[d * 64 + j];
        aK[0] = fmaf(xv.x, kw, aK[0]); aV[0] = fmaf(xv.x, vw, aV[0]);
        aK[1] = fmaf(xv.y, kw, aK[1]); aV[1] = fmaf(xv.y, vw, aV[1]);
        aK[2] = fmaf(xv.z, kw, aK[2]); aV[2] = fmaf(xv.z, vw, aV[2]);
        aK[3] = fmaf(xv.w, kw, aK[3]); aV[3] = fmaf(xv.w, vw, aV[3]);
    }
    size_t base = ((size_t)b * NSEQ + m0) * 64 + j;
    #pragma unroll
    for (int i = 0; i < 4; ++i) {
        unsigned short hi = f2bf(aK[i]);
        kkhi[base + i * 64] = hi;
        kklo[base + i * 64] = f2bf(aK[i] - bf2f(hi));
        vbuf[j * 17 + g * 4 + i] = aV[i];
    }
    __syncthreads();
    int v = tid >> 2, mq = tid & 3;
    int b2 = blockIdx.x >> 7;
    int mb = (blockIdx.x & 127) * 16 + mq * 4;
    size_t vb = ((size_t)b2 * 64 + v) * NSEQ + mb;
    ushort4 hv, lv;
    #pragma unroll
    for (int i2 = 0; i2 < 4; ++i2) {
        float vv_ = vbuf[v * 17 + mq * 4 + i2];
        unsigned short hi = f2bf(vv_);
        ((unsigned short*)&hv)[i2] = hi;
        ((unsigned short*)&lv)[i2] = f2bf(vv_ - bf2f(hi));
    }
    *(ushort4*)(vthi + vb) = hv;
    *(ushort4*)(vtlo + vb) = lv;
}

// ---------------------------------------------------------------------------
// Kernel 2: x transpose+convert: x fp32 [b][d][n] -> xT hi/lo bf16 [b][n][d]
// (d contiguous = ready-made MFMA B-fragments for the projections).
// ---------------------------------------------------------------------------
__global__ __launch_bounds__(256) void xt_kernel(
    const float* __restrict__ x, unsigned short* __restrict__ xthi,
    unsigned short* __restrict__ xtlo)
{
    __shared__ float tile[64 * 68];
    int t = threadIdx.x;
    int b = blockIdx.z, d0 = blockIdx.y * 64, n0 = blockIdx.x * 64;
    int dl = t >> 4, n4 = (t & 15) * 4;
    #pragma unroll
    for (int i = 0; i < 4; ++i) {
        int d = dl + i * 16;
        float4 v = *(const float4*)(x + ((size_t)b * DDIM + d0 + d) * NSEQ + n0 + n4);
        *(float4*)(tile + d * 68 + n4) = v;
    }
    __syncthreads();
    int nl = t >> 2, dq = (t & 3) * 16;
    size_t base = ((size_t)b * NSEQ + n0 + nl) * DDIM + d0 + dq;
    #pragma unroll
    for (int g = 0; g < 4; ++g) {
        ushort4 hv, lv;
        #pragma unroll
        for (int k = 0; k < 4; ++k) {
            float v = tile[(dq + g * 4 + k) * 68 + nl];
            unsigned short hi = f2bf(v);
            ((unsigned short*)&hv)[k] = hi;
            ((unsigned short*)&lv)[k] = f2bf(v - bf2f(hi));
        }
        *(ushort4*)(xthi + base + g * 4) = hv;
        *(ushort4*)(xtlo + base + g * 4) = lv;
    }
}

// ---------------------------------------------------------------------------
// Kernel 3: weight convert: qp (h,k,d) -> qphi/qplo (0.125 scale folded);
// op (d,hv) -> ophi/oplo. Same layouts (contraction dim already contiguous).
// ---------------------------------------------------------------------------
__global__ __launch_bounds__(256) void wconv_kernel(
    const float* __restrict__ qp, const float* __restrict__ op,
    unsigned short* __restrict__ qphi, unsigned short* __restrict__ qplo,
    unsigned short* __restrict__ ophi, unsigned short* __restrict__ oplo)
{
    int e = (blockIdx.x * 256 + threadIdx.x) * 4;
    const float* src = blockIdx.y ? op : qp;
    unsigned short* dh = blockIdx.y ? ophi : qphi;
    unsigned short* dl = blockIdx.y ? oplo : qplo;
    float sc = blockIdx.y ? 1.0f : 0.125f;   // fold 1/sqrt(64) into qp
    float4 v = *(const float4*)(src + e);
    v.x *= sc; v.y *= sc; v.z *= sc; v.w *= sc;
    ushort4 hv, lv;
    hv.x = f2bf(v.x); lv.x = f2bf(v.x - bf2f(hv.x));
    hv.y = f2bf(v.y); lv.y = f2bf(v.y - bf2f(hv.y));
    hv.z = f2bf(v.z); lv.z = f2bf(v.z - bf2f(hv.z));
    hv.w = f2bf(v.w); lv.w = f2bf(v.w - bf2f(hv.w));
    *(ushort4*)(dh + e) = hv;
    *(ushort4*)(dl + e) = lv;
}

// ---------------------------------------------------------------------------
// Kernel 4: Q projection, MFMA. Block = (128-n tile, h, b), 4 waves.
// D[k][n] = qp[k][d] · xT[n][d]^T, contraction d=512 in 8 steps of 64.
// Wave w owns k-sub w (16 k) x 128 n. xT hi/lo tiles double-buffered in LDS
// via global_load_lds with XOR-granule swizzle; A-frags (qp) direct global.
// 3-pass hi/lo. Epilogue: LDS transpose -> q hi/lo bf16 [b][h][n][64].
// ---------------------------------------------------------------------------
__global__ __launch_bounds__(256, 2) void q_proj_kernel(
    const unsigned short* __restrict__ xthi, const unsigned short* __restrict__ xtlo,
    const unsigned short* __restrict__ qphi, const unsigned short* __restrict__ qplo,
    unsigned short* __restrict__ qhi, unsigned short* __restrict__ qlo)
{
    __shared__ __align__(128) char arena[65536];  // dbuf x (hi 16K | lo 16K)
    const int tid = threadIdx.x;
    const int w = tid >> 6, l = tid & 63;
    const int qd = l >> 4, ln = l & 15;
    const int b = blockIdx.z, h = blockIdx.y;
    const int n0 = blockIdx.x * 128;

    const int vrow = l >> 3, gsw = (l & 7) ^ vrow;
    const int tsel = w >> 1;                 // 0: hi tensor, 1: lo tensor
    const int rhalf = (w & 1) * 64;          // row half
    const char* sb = (const char*)(tsel ? xtlo : xthi)
        + ((size_t)(b * NSEQ + n0 + rhalf) * DDIM) * 2
        + (size_t)vrow * 1024 + (size_t)gsw * 16;
    char* dst0 = arena + tsel * 16384 + rhalf * 128;

    auto stage = [&](int buf, int s) {
        const char* gg = sb + (size_t)s * 128;
        char* dd = dst0 + buf * 32768;
        #pragma unroll
        for (int i = 0; i < 8; ++i)
            __builtin_amdgcn_global_load_lds(
                (const __attribute__((address_space(1))) unsigned int*)(gg + (size_t)i * 8192),
                (__attribute__((address_space(3))) unsigned int*)(dd + i * 1024),
                16, 0, 0);
    };

    f32x4 acc[8];
    const f32x4 vzero = {0.f, 0.f, 0.f, 0.f};
    #pragma unroll
    for (int i = 0; i < 8; ++i) acc[i] = vzero;

    const unsigned short* qpb_h = qphi + ((size_t)h * 64 + w * 16 + ln) * DDIM;
    const unsigned short* qpb_l = qplo + ((size_t)h * 64 + w * 16 + ln) * DDIM;

    stage(0, 0);
    for (int s = 0; s < 8; ++s) {
        int buf = s & 1;
        __syncthreads();
        if (s + 1 < 8) stage(buf ^ 1, s + 1);
        const char* Bh = arena + buf * 32768;
        const char* Bl = Bh + 16384;
        #pragma unroll
        for (int hh = 0; hh < 2; ++hh) {
            s16x8 ah = *(const s16x8*)(qpb_h + s * 64 + hh * 32 + qd * 8);
            s16x8 al = *(const s16x8*)(qpb_l + s * 64 + hh * 32 + qd * 8);
            int goff = ((hh * 4 + qd) ^ (ln & 7)) * 16;
            #pragma unroll
            for (int ns = 0; ns < 8; ++ns) {
                int ro = (ns * 16 + ln) * 128 + goff;
                s16x8 bh = *(const s16x8*)(Bh + ro);
                s16x8 bl = *(const s16x8*)(Bl + ro);
                acc[ns] = mfma32(ah, bh, acc[ns]);
                acc[ns] = mfma32(ah, bl, acc[ns]);
                acc[ns] = mfma32(al, bh, acc[ns]);
            }
        }
    }
    // epilogue: transpose via LDS -> [n][k], then hi/lo split store
    __syncthreads();
    float* eb = (float*)arena;    // [128 n][69 pad] fp32 = 35 KB
    #pragma unroll
    for (int ns = 0; ns < 8; ++ns)
        #pragma unroll
        for (int r = 0; r < 4; ++r)
            eb[(ns * 16 + ln) * 69 + w * 16 + qd * 4 + r] = acc[ns][r];
    __syncthreads();
    {
        int n = tid >> 1, half = tid & 1;
        size_t base = (((size_t)b * NHEAD + h) * NSEQ + n0 + n) * 64 + half * 32;
        #pragma unroll
        for (int g = 0; g < 8; ++g) {
            ushort4 hv, lv;
            #pragma unroll
            for (int k = 0; k < 4; ++k) {
                float v = eb[n * 69 + half * 32 + g * 4 + k];
                unsigned short hi = f2bf(v);
                ((unsigned short*)&hv)[k] = hi;
                ((unsigned short*)&lv)[k] = f2bf(v - bf2f(hi));
            }
            *(ushort4*)(qhi + base + g * 4) = hv;
            *(ushort4*)(qlo + base + g * 4) = lv;
        }
    }
}

// ---------------------------------------------------------------------------
// Kernel 5: MFMA flash attention. Unchanged from round 3.
// ---------------------------------------------------------------------------
__global__ __launch_bounds__(256, 2) void attn_kernel(
    const unsigned short* __restrict__ kkhi, const unsigned short* __restrict__ kklo,
    const unsigned short* __restrict__ vthi, const unsigned short* __restrict__ vtlo,
    const unsigned short* __restrict__ qhi,  const unsigned short* __restrict__ qlo,
    unsigned short* __restrict__ obf)
{
    __shared__ __align__(128) char arena[65536];  // [2 bufs][Khi|Klo|VThi|VTlo] 8KB each

    const int tid = threadIdx.x;
    const int w  = tid >> 6;        // wave 0..3 = m-subtile owner
    const int l  = tid & 63;
    const int qd = l >> 4;          // quad
    const int ln = l & 15;
    const int bz = blockIdx.z, hz = blockIdx.y;
    const int n0 = blockIdx.x * 64;

    s16x8 qh[4][2], qlo_[4][2];
    {
        size_t rowb = (((size_t)bz * NHEAD + hz) * NSEQ + n0 + ln) * 64 + qd * 8;
        #pragma unroll
        for (int t = 0; t < 4; ++t)
            #pragma unroll
            for (int c = 0; c < 2; ++c) {
                qh[t][c]   = *(const s16x8*)(qhi + rowb + (size_t)t * 16 * 64 + c * 32);
                qlo_[t][c] = *(const s16x8*)(qlo + rowb + (size_t)t * 16 * 64 + c * 32);
            }
    }

    const int vrow = l >> 3;
    const int gsw  = (l & 7) ^ vrow;
    const char* sb; int rs, ts;
    if      (w == 0) { sb = (const char*)kkhi; rs = 128;  ts = 8192; }
    else if (w == 1) { sb = (const char*)kklo; rs = 128;  ts = 8192; }
    else if (w == 2) { sb = (const char*)vthi; rs = 4096; ts = 128;  }
    else             { sb = (const char*)vtlo; rs = 4096; ts = 128;  }
    sb += (size_t)bz * 262144 + (size_t)vrow * rs + (size_t)gsw * 16;
    char* ldst0 = arena + w * 8192;

    auto stage = [&](int buf, int mt) {
        const char* gg = sb + (size_t)mt * ts;
        char* dst = ldst0 + buf * 32768;
        #pragma unroll
        for (int i = 0; i < 8; ++i) {
            __builtin_amdgcn_global_load_lds(
                (const __attribute__((address_space(1))) unsigned int*)(gg + (size_t)i * 8 * rs),
                (__attribute__((address_space(3))) unsigned int*)(dst + i * 1024),
                16, 0, 0);
        }
    };

    int offK[2], offV[4];
    #pragma unroll
    for (int c = 0; c < 2; ++c)
        offK[c] = (w * 16 + ln) * 128 + (((c * 4 + qd) ^ (ln & 7)) * 16);
    #pragma unroll
    for (int s = 0; s < 4; ++s)
        offV[s] = (s * 16 + ln) * 128 + (((2 * w + (qd >> 1)) ^ (ln & 7)) * 16) + (qd & 1) * 8;

    f32x4 O[4][4];
    const f32x4 vzero = {0.f, 0.f, 0.f, 0.f};
    #pragma unroll
    for (int s = 0; s < 4; ++s)
        #pragma unroll
        for (int t = 0; t < 4; ++t) O[s][t] = vzero;
    float mi[4], li[4];
    #pragma unroll
    for (int t = 0; t < 4; ++t) { mi[t] = -1e30f; li[t] = 0.f; }

    stage(0, 0);

    for (int mt = 0; mt < 32; ++mt) {
        int buf = mt & 1;
        __syncthreads();
        if (mt + 1 < 32) stage(buf ^ 1, mt + 1);
        const char* Kh = arena + buf * 32768;
        const char* Kl = Kh + 8192;
        const char* Vh = Kh + 16384;
        const char* Vl = Kh + 24576;

        s16x8 kh[2], kl[2];
        #pragma unroll
        for (int c = 0; c < 2; ++c) {
            kh[c] = *(const s16x8*)(Kh + offK[c]);
            kl[c] = *(const s16x8*)(Kl + offK[c]);
        }
        f32x4 S[4];
        #pragma unroll
        for (int t = 0; t < 4; ++t) S[t] = vzero;
        #pragma unroll
        for (int c = 0; c < 2; ++c)
            #pragma unroll
            for (int t = 0; t < 4; ++t) {
                S[t] = mfma32(kh[c], qh[t][c],   S[t]);
                S[t] = mfma32(kh[c], qlo_[t][c], S[t]);
                S[t] = mfma32(kl[c], qh[t][c],   S[t]);
            }

        s16x4 pb[4]; float corr[4];
        #pragma unroll
        for (int t = 0; t < 4; ++t) {
            float rmax = fmaxf(fmaxf(S[t][0], S[t][1]), fmaxf(S[t][2], S[t][3]));
            rmax = fmaxf(rmax, __shfl_xor(rmax, 16, 64));
            rmax = fmaxf(rmax, __shfl_xor(rmax, 32, 64));
            float mnew = fmaxf(mi[t], rmax);
            corr[t] = __expf(mi[t] - mnew);
            mi[t] = mnew;
            float p0 = __expf(S[t][0] - mnew);
            float p1 = __expf(S[t][1] - mnew);
            float p2 = __expf(S[t][2] - mnew);
            float p3 = __expf(S[t][3] - mnew);
            float ps = p0 + p1 + p2 + p3;
            ps += __shfl_xor(ps, 16, 64);
            ps += __shfl_xor(ps, 32, 64);
            li[t] = li[t] * corr[t] + ps;
            s16x4 pv;
            pv[0] = (short)f2bf(p0); pv[1] = (short)f2bf(p1);
            pv[2] = (short)f2bf(p2); pv[3] = (short)f2bf(p3);
            pb[t] = pv;
        }
        #pragma unroll
        for (int s = 0; s < 4; ++s)
            #pragma unroll
            for (int t = 0; t < 4; ++t)
                O[s][t] *= corr[t];
        #pragma unroll
        for (int s = 0; s < 4; ++s) {
            s16x4 vh = *(const s16x4*)(Vh + offV[s]);
            s16x4 vl = *(const s16x4*)(Vl + offV[s]);
            #pragma unroll
            for (int t = 0; t < 4; ++t) {
                O[s][t] = mfma16(vh, pb[t], O[s][t]);
                O[s][t] = mfma16(vl, pb[t], O[s][t]);
            }
        }
    }

    float* obuf  = (float*)arena;
    float* mlm   = (float*)(arena + 4608);
    float* mll   = (float*)(arena + 5632);
    float* linvs = (float*)(arena + 6656);

    if (qd == 0) {
        #pragma unroll
        for (int t = 0; t < 4; ++t) {
            mlm[w * 64 + t * 16 + ln] = mi[t];
            mll[w * 64 + t * 16 + ln] = li[t];
        }
    }
    __syncthreads();
    float f[4];
    #pragma unroll
    for (int t = 0; t < 4; ++t) {
        float M = mlm[t * 16 + ln];
        M = fmaxf(M, mlm[64 + t * 16 + ln]);
        M = fmaxf(M, mlm[128 + t * 16 + ln]);
        M = fmaxf(M, mlm[192 + t * 16 + ln]);
        float L = 0.f;
        #pragma unroll
        for (int ww = 0; ww < 4; ++ww)
            L += mll[ww * 64 + t * 16 + ln] * __expf(mlm[ww * 64 + t * 16 + ln] - M);
        f[t] = __expf(mi[t] - M);
        if (w == 0 && qd == 0) linvs[t * 16 + ln] = 1.0f / L;
    }

    #pragma unroll
    for (int t = 0; t < 4; ++t) {
        #pragma unroll
        for (int r = 0; r < 4; ++r) {
            __syncthreads();
            #pragma unroll
            for (int s = 0; s < 4; ++s) {
                if (((w + r) & 3) == s) {
                    f32x4 val = O[s][t] * f[t];
                    float* dst = obuf + (s * 16 + qd * 4) * 17 + ln;
                    if (r == 0) {
                        dst[0]  = val[0]; dst[17] = val[1];
                        dst[34] = val[2]; dst[51] = val[3];
                    } else {
                        dst[0]  += val[0]; dst[17] += val[1];
                        dst[34] += val[2]; dst[51] += val[3];
                    }
                }
            }
        }
        __syncthreads();
        int vq = tid & 15, nl = tid >> 4;
        float il = linvs[t * 16 + nl];
        ushort4 u4;
        u4.x = f2bf(obuf[(vq * 4 + 0) * 17 + nl] * il);
        u4.y = f2bf(obuf[(vq * 4 + 1) * 17 + nl] * il);
        u4.z = f2bf(obuf[(vq * 4 + 2) * 17 + nl] * il);
        u4.w = f2bf(obuf[(vq * 4 + 3) * 17 + nl] * il);
        *(ushort4*)(obf + (((size_t)bz * NSEQ + n0 + t * 16 + nl) * 512) + hz * 64 + vq * 4) = u4;
    }
}

// ---------------------------------------------------------------------------
// Kernel 6: output projection, MFMA. Block = (128-n tile, 64-d tile, b).
// D[d][n] = op[d][hv] · o[n][hv]^T, 2-pass (op hi + op lo, o is bf16).
// o tiles double-buffered in LDS (XOR-granule swizzle); op A-frags direct.
// C-layout direct stores: 4 x 64 B segments/instr.
// ---------------------------------------------------------------------------
__global__ __launch_bounds__(256, 2) void out_proj_kernel(
    const unsigned short* __restrict__ obf,
    const unsigned short* __restrict__ ophi, const unsigned short* __restrict__ oplo,
    float* __restrict__ out)
{
    __shared__ __align__(128) char arena[32768];  // dbuf x 16 KB
    const int tid = threadIdx.x;
    const int w = tid >> 6, l = tid & 63;
    const int qd = l >> 4, ln = l & 15;
    const int b = blockIdx.z, d0 = blockIdx.y * 64;
    const int n0 = blockIdx.x * 128;
    const int vrow = l >> 3, gsw = (l & 7) ^ vrow;

    const char* sb = (const char*)obf
        + ((size_t)(b * NSEQ + n0 + w * 32) * 512) * 2
        + (size_t)vrow * 1024 + (size_t)gsw * 16;
    char* dst0 = arena + w * 32 * 128;

    auto stage = [&](int buf, int s) {
        const char* gg = sb + (size_t)s * 128;
        char* dd = dst0 + buf * 16384;
        #pragma unroll
        for (int i = 0; i < 4; ++i)
            __builtin_amdgcn_global_load_lds(
                (const __attribute__((address_space(1))) unsigned int*)(gg + (size_t)i * 8192),
                (__attribute__((address_space(3))) unsigned int*)(dd + i * 1024),
                16, 0, 0);
    };

    f32x4 acc[8];
    const f32x4 vzero = {0.f, 0.f, 0.f, 0.f};
    #pragma unroll
    for (int i = 0; i < 8; ++i) acc[i] = vzero;

    const unsigned short* oph = ophi + (size_t)(d0 + w * 16 + ln) * 512;
    const unsigned short* opl = oplo + (size_t)(d0 + w * 16 + ln) * 512;

    stage(0, 0);
    for (int s = 0; s < 8; ++s) {
        int buf = s & 1;
        __syncthreads();
        if (s + 1 < 8) stage(buf ^ 1, s + 1);
        const char* Bt = arena + buf * 16384;
        #pragma unroll
        for (int hh = 0; hh < 2; ++hh) {
            s16x8 ah = *(const s16x8*)(oph + s * 64 + hh * 32 + qd * 8);
            s16x8 al = *(const s16x8*)(opl + s * 64 + hh * 32 + qd * 8);
            int goff = ((hh * 4 + qd) ^ (ln & 7)) * 16;
            #pragma unroll
            for (int ns = 0; ns < 8; ++ns) {
                s16x8 bb = *(const s16x8*)(Bt + (ns * 16 + ln) * 128 + goff);
                acc[ns] = mfma32(ah, bb, acc[ns]);
                acc[ns] = mfma32(al, bb, acc[ns]);
            }
        }
    }
    #pragma unroll
    for (int ns = 0; ns < 8; ++ns)
        #pragma unroll
        for (int r = 0; r < 4; ++r)
            out[((size_t)b * DDIM + d0 + w * 16 + qd * 4 + r) * NSEQ
                + n0 + ns * 16 + ln] = acc[ns][r];
}

// ---------------------------------------------------------------------------
extern "C" void kernel_launch(void* const* d_in, const int* in_sizes, int n_in,
                              void* d_out, int out_size, void* d_ws, size_t ws_size,
                              hipStream_t stream) {
    const float* x  = (const float*)d_in[0];   // (2,512,2048)
    const float* qp = (const float*)d_in[1];   // (8,64,512)
    const float* kp = (const float*)d_in[2];   // (512,64)
    const float* vp = (const float*)d_in[3];   // (512,64)
    const float* op = (const float*)d_in[4];   // (512,8,64)
    float* out = (float*)d_out;                // (2,512,2048)

    // Workspace (shorts), ~21 MB total. obf aliases xthi (xT dead after q_proj).
    unsigned short* ws   = (unsigned short*)d_ws;
    unsigned short* kkhi = ws;                   // 262144
    unsigned short* kklo = kkhi + 262144;
    unsigned short* vthi = kklo + 262144;
    unsigned short* vtlo = vthi + 262144;
    unsigned short* qphi = vtlo + 262144;
    unsigned short* qplo = qphi + 262144;
    unsigned short* ophi = qplo + 262144;
    unsigned short* oplo = ophi + 262144;
    unsigned short* xthi = oplo + 262144;        // 2097152
    unsigned short* xtlo = xthi + 2097152;
    unsigned short* qhi  = xtlo + 2097152;
    unsigned short* qlo  = qhi + 2097152;
    unsigned short* obf  = xthi;                 // alias

    hipLaunchKernelGGL(kv_proj_kernel,  dim3(256),       dim3(256), 0, stream,
                       x, kp, vp, kkhi, kklo, vthi, vtlo);
    hipLaunchKernelGGL(xt_kernel,       dim3(32, 8, 2),  dim3(256), 0, stream,
                       x, xthi, xtlo);
    hipLaunchKernelGGL(wconv_kernel,    dim3(256, 2),    dim3(256), 0, stream,
                       qp, op, qphi, qplo, ophi, oplo);
    hipLaunchKernelGGL(q_proj_kernel,   dim3(16, 8, 2),  dim3(256), 0, stream,
                       xthi, xtlo, qphi, qplo, qhi, qlo);
    hipLaunchKernelGGL(attn_kernel,     dim3(32, 8, 2),  dim3(256), 0, stream,
                       kkhi, kklo, vthi, vtlo, qhi, qlo, obf);
    hipLaunchKernelGGL(out_proj_kernel, dim3(16, 8, 2),  dim3(256), 0, stream,
                       obf, ophi, oplo, out);
}

// Round 5
// 189.209 us; speedup vs baseline: 4.4984x; 1.1918x over previous
//
#include <hip/hip_runtime.h>
#include <math.h>

// Problem constants: B=2, D=512, N=M=2048, H=8, K=V=64
#define BB 2
#define DDIM 512
#define NSEQ 2048
#define NHEAD 8

typedef __attribute__((ext_vector_type(4))) short s16x4;
typedef __attribute__((ext_vector_type(8))) short s16x8;
typedef __attribute__((ext_vector_type(4))) float f32x4;

__device__ __forceinline__ unsigned short f2bf(float f) {
    unsigned u = __float_as_uint(f);
    u = (u + 0x7FFFu + ((u >> 16) & 1u)) >> 16;   // RNE
    return (unsigned short)u;
}
__device__ __forceinline__ float bf2f(unsigned short h) {
    return __uint_as_float(((unsigned)h) << 16);
}

__device__ __forceinline__ f32x4 mfma32(s16x8 a, s16x8 b, f32x4 c) {
    return __builtin_amdgcn_mfma_f32_16x16x32_bf16(a, b, c, 0, 0, 0);
}
__device__ __forceinline__ f32x4 mfma16(s16x4 a, s16x4 b, f32x4 c) {
#if __has_builtin(__builtin_amdgcn_mfma_f32_16x16x16bf16_1k)
    return __builtin_amdgcn_mfma_f32_16x16x16bf16_1k(a, b, c, 0, 0, 0);
#else
    s16x8 a8 = { a[0], a[1], a[2], a[3], 0, 0, 0, 0 };
    s16x8 b8 = { b[0], b[1], b[2], b[3], 0, 0, 0, 0 };
    return __builtin_amdgcn_mfma_f32_16x16x32_bf16(a8, b8, c, 0, 0, 0);
#endif
}

// ---------------------------------------------------------------------------
// Kernel 1: x transpose+convert: x fp32 [b][d][n] -> xT hi/lo bf16 [b][n][d].
// ---------------------------------------------------------------------------
__global__ __launch_bounds__(256) void xt_kernel(
    const float* __restrict__ x, unsigned short* __restrict__ xthi,
    unsigned short* __restrict__ xtlo)
{
    __shared__ float tile[64 * 68];
    int t = threadIdx.x;
    int b = blockIdx.z, d0 = blockIdx.y * 64, n0 = blockIdx.x * 64;
    int dl = t >> 4, n4 = (t & 15) * 4;
    #pragma unroll
    for (int i = 0; i < 4; ++i) {
        int d = dl + i * 16;
        float4 v = *(const float4*)(x + ((size_t)b * DDIM + d0 + d) * NSEQ + n0 + n4);
        *(float4*)(tile + d * 68 + n4) = v;
    }
    __syncthreads();
    int nl = t >> 2, dq = (t & 3) * 16;
    size_t base = ((size_t)b * NSEQ + n0 + nl) * DDIM + d0 + dq;
    #pragma unroll
    for (int g = 0; g < 4; ++g) {
        ushort4 hv, lv;
        #pragma unroll
        for (int k = 0; k < 4; ++k) {
            float v = tile[(dq + g * 4 + k) * 68 + nl];
            unsigned short hi = f2bf(v);
            ((unsigned short*)&hv)[k] = hi;
            ((unsigned short*)&lv)[k] = f2bf(v - bf2f(hi));
        }
        *(ushort4*)(xthi + base + g * 4) = hv;
        *(ushort4*)(xtlo + base + g * 4) = lv;
    }
}

// ---------------------------------------------------------------------------
// Kernel 2: weight convert: qp (0.125 folded) and op -> hi/lo bf16, layouts
// unchanged (contraction dim already contiguous).
// ---------------------------------------------------------------------------
__global__ __launch_bounds__(256) void wconv_kernel(
    const float* __restrict__ qp, const float* __restrict__ op,
    unsigned short* __restrict__ qphi, unsigned short* __restrict__ qplo,
    unsigned short* __restrict__ ophi, unsigned short* __restrict__ oplo)
{
    int e = (blockIdx.x * 256 + threadIdx.x) * 4;
    const float* src = blockIdx.y ? op : qp;
    unsigned short* dh = blockIdx.y ? ophi : qphi;
    unsigned short* dl = blockIdx.y ? oplo : qplo;
    float sc = blockIdx.y ? 1.0f : 0.125f;
    float4 v = *(const float4*)(src + e);
    v.x *= sc; v.y *= sc; v.z *= sc; v.w *= sc;
    ushort4 hv, lv;
    hv.x = f2bf(v.x); lv.x = f2bf(v.x - bf2f(hv.x));
    hv.y = f2bf(v.y); lv.y = f2bf(v.y - bf2f(hv.y));
    hv.z = f2bf(v.z); lv.z = f2bf(v.z - bf2f(hv.z));
    hv.w = f2bf(v.w); lv.w = f2bf(v.w - bf2f(hv.w));
    *(ushort4*)(dh + e) = hv;
    *(ushort4*)(dl + e) = lv;
}

// ---------------------------------------------------------------------------
// Kernel 3: K/V weight transpose+convert: kp/vp fp32 [d][64] -> [64 j][512 d]
// hi/lo bf16 (d contiguous = MFMA A-fragment-ready).
// ---------------------------------------------------------------------------
__global__ __launch_bounds__(256) void kvw_kernel(
    const float* __restrict__ kp, const float* __restrict__ vp,
    unsigned short* __restrict__ kpthi, unsigned short* __restrict__ kptlo,
    unsigned short* __restrict__ vpthi, unsigned short* __restrict__ vptlo)
{
    __shared__ float tile[64 * 68];
    int t = threadIdx.x;
    int d0 = blockIdx.x * 64;
    const float* src = blockIdx.y ? vp : kp;
    unsigned short* dsth = blockIdx.y ? vpthi : kpthi;
    unsigned short* dstl = blockIdx.y ? vptlo : kptlo;
    int dl = t >> 4, j4 = (t & 15) * 4;
    #pragma unroll
    for (int i = 0; i < 4; ++i) {
        int d = dl + i * 16;
        float4 v = *(const float4*)(src + (size_t)(d0 + d) * 64 + j4);
        *(float4*)(tile + d * 68 + j4) = v;
    }
    __syncthreads();
    int jl = t >> 2, dq = (t & 3) * 16;
    #pragma unroll
    for (int g = 0; g < 4; ++g) {
        ushort4 hv, lv;
        #pragma unroll
        for (int k = 0; k < 4; ++k) {
            float v = tile[(dq + g * 4 + k) * 68 + jl];
            unsigned short hi = f2bf(v);
            ((unsigned short*)&hv)[k] = hi;
            ((unsigned short*)&lv)[k] = f2bf(v - bf2f(hi));
        }
        *(ushort4*)(dsth + (size_t)jl * DDIM + d0 + dq + g * 4) = hv;
        *(ushort4*)(dstl + (size_t)jl * DDIM + d0 + dq + g * 4) = lv;
    }
}

// ---------------------------------------------------------------------------
// Kernel 4: K/V projection, MFMA (replaces latency-bound fp32 version that
// ran 82us at VALUBusy=6%). Block = (64-m tile, b), 4 waves.
// D[j][m] = w[j][d] · xT[m][d]^T, d=512 in 8 steps of 64. Wave w: tensor =
// w>>1 (K or V), j-half = w&1. xT hi/lo tiles double-buffered in LDS via
// global_load_lds + XOR-granule swizzle; weight A-frags direct (L1-cached).
// 3-pass hi/lo. K epilogue: LDS transpose -> kk hi/lo [b][m][64]. V epilogue:
// direct C-layout stores -> vt hi/lo [b][v][m] (lane=m matches V^T natively).
// ---------------------------------------------------------------------------
__global__ __launch_bounds__(256, 2) void kv_proj_kernel(
    const unsigned short* __restrict__ xthi, const unsigned short* __restrict__ xtlo,
    const unsigned short* __restrict__ kpthi, const unsigned short* __restrict__ kptlo,
    const unsigned short* __restrict__ vpthi, const unsigned short* __restrict__ vptlo,
    unsigned short* __restrict__ kkhi, unsigned short* __restrict__ kklo,
    unsigned short* __restrict__ vthi, unsigned short* __restrict__ vtlo)
{
    __shared__ __align__(128) char arena[32768];  // dbuf x (hi 8K | lo 8K)
    const int tid = threadIdx.x;
    const int w = tid >> 6, l = tid & 63;
    const int qd = l >> 4, ln = l & 15;
    const int b = blockIdx.y;
    const int m0 = blockIdx.x * 64;

    // staging role: waves 0,1 stage hi tensor halves; 2,3 stage lo
    const int vrow = l >> 3, gsw = (l & 7) ^ vrow;
    const int tsel = w >> 1;
    const int mhalf = (w & 1) * 32;
    const char* sxb = (const char*)(tsel ? xtlo : xthi)
        + ((size_t)(b * NSEQ + m0 + mhalf) * DDIM) * 2
        + (size_t)vrow * 1024 + (size_t)gsw * 16;
    char* dst0 = arena + tsel * 8192 + mhalf * 128;

    auto stage = [&](int buf, int s) {
        const char* gg = sxb + (size_t)s * 128;
        char* dd = dst0 + buf * 16384;
        #pragma unroll
        for (int i = 0; i < 4; ++i)
            __builtin_amdgcn_global_load_lds(
                (const __attribute__((address_space(1))) unsigned int*)(gg + (size_t)i * 8 * 1024),
                (__attribute__((address_space(3))) unsigned int*)(dd + i * 1024),
                16, 0, 0);
    };

    // compute role: K for waves 0,1; V for waves 2,3; j-half = w&1
    const int isV = w >> 1;
    const int jh  = w & 1;
    const unsigned short* wh = (isV ? vpthi : kpthi) + (size_t)(jh * 32) * DDIM;
    const unsigned short* wl = (isV ? vptlo : kptlo) + (size_t)(jh * 32) * DDIM;

    f32x4 acc[2][4];   // [j-sub][m-sub]
    const f32x4 vzero = {0.f, 0.f, 0.f, 0.f};
    #pragma unroll
    for (int js = 0; js < 2; ++js)
        #pragma unroll
        for (int ms = 0; ms < 4; ++ms) acc[js][ms] = vzero;

    stage(0, 0);
    for (int s = 0; s < 8; ++s) {
        int buf = s & 1;
        __syncthreads();
        if (s + 1 < 8) stage(buf ^ 1, s + 1);
        const char* Bh = arena + buf * 16384;
        const char* Bl = Bh + 8192;
        #pragma unroll
        for (int hh = 0; hh < 2; ++hh) {
            s16x8 ah[2], al[2];
            #pragma unroll
            for (int js = 0; js < 2; ++js) {
                size_t ao = (size_t)(js * 16 + ln) * DDIM + s * 64 + hh * 32 + qd * 8;
                ah[js] = *(const s16x8*)(wh + ao);
                al[js] = *(const s16x8*)(wl + ao);
            }
            int goff = ((hh * 4 + qd) ^ (ln & 7)) * 16;
            #pragma unroll
            for (int ms = 0; ms < 4; ++ms) {
                int ro = (ms * 16 + ln) * 128 + goff;
                s16x8 bh = *(const s16x8*)(Bh + ro);
                s16x8 bl = *(const s16x8*)(Bl + ro);
                #pragma unroll
                for (int js = 0; js < 2; ++js) {
                    acc[js][ms] = mfma32(ah[js], bh, acc[js][ms]);
                    acc[js][ms] = mfma32(ah[js], bl, acc[js][ms]);
                    acc[js][ms] = mfma32(al[js], bh, acc[js][ms]);
                }
            }
        }
    }

    // ---- V epilogue: direct stores (C-layout lane=m is V^T's layout) ----
    if (isV) {
        #pragma unroll
        for (int js = 0; js < 2; ++js)
            #pragma unroll
            for (int ms = 0; ms < 4; ++ms)
                #pragma unroll
                for (int r = 0; r < 4; ++r) {
                    int v = jh * 32 + js * 16 + qd * 4 + r;
                    size_t o = ((size_t)b * 64 + v) * NSEQ + m0 + ms * 16 + ln;
                    float val = acc[js][ms][r];
                    unsigned short hi = f2bf(val);
                    vthi[o] = hi;
                    vtlo[o] = f2bf(val - bf2f(hi));
                }
    }
    // ---- K epilogue: LDS transpose -> [m][j], split, coalesced stores ----
    __syncthreads();
    float* eb = (float*)arena;   // [64 m][66 pad] fp32 = 16.9 KB
    if (!isV) {
        #pragma unroll
        for (int js = 0; js < 2; ++js)
            #pragma unroll
            for (int ms = 0; ms < 4; ++ms)
                #pragma unroll
                for (int r = 0; r < 4; ++r)
                    eb[(ms * 16 + ln) * 66 + jh * 32 + js * 16 + qd * 4 + r]
                        = acc[js][ms][r];
    }
    __syncthreads();
    {
        int m = tid >> 2, jg = (tid & 3) * 16;
        size_t base = ((size_t)b * NSEQ + m0 + m) * 64 + jg;
        #pragma unroll
        for (int g = 0; g < 4; ++g) {
            ushort4 hv, lv;
            #pragma unroll
            for (int k = 0; k < 4; ++k) {
                float v = eb[m * 66 + jg + g * 4 + k];
                unsigned short hi = f2bf(v);
                ((unsigned short*)&hv)[k] = hi;
                ((unsigned short*)&lv)[k] = f2bf(v - bf2f(hi));
            }
            *(ushort4*)(kkhi + base + g * 4) = hv;
            *(ushort4*)(kklo + base + g * 4) = lv;
        }
    }
}

// ---------------------------------------------------------------------------
// Kernel 5: Q projection, MFMA. Unchanged from round 4.
// ---------------------------------------------------------------------------
__global__ __launch_bounds__(256, 2) void q_proj_kernel(
    const unsigned short* __restrict__ xthi, const unsigned short* __restrict__ xtlo,
    const unsigned short* __restrict__ qphi, const unsigned short* __restrict__ qplo,
    unsigned short* __restrict__ qhi, unsigned short* __restrict__ qlo)
{
    __shared__ __align__(128) char arena[65536];  // dbuf x (hi 16K | lo 16K)
    const int tid = threadIdx.x;
    const int w = tid >> 6, l = tid & 63;
    const int qd = l >> 4, ln = l & 15;
    const int b = blockIdx.z, h = blockIdx.y;
    const int n0 = blockIdx.x * 128;

    const int vrow = l >> 3, gsw = (l & 7) ^ vrow;
    const int tsel = w >> 1;
    const int rhalf = (w & 1) * 64;
    const char* sb = (const char*)(tsel ? xtlo : xthi)
        + ((size_t)(b * NSEQ + n0 + rhalf) * DDIM) * 2
        + (size_t)vrow * 1024 + (size_t)gsw * 16;
    char* dst0 = arena + tsel * 16384 + rhalf * 128;

    auto stage = [&](int buf, int s) {
        const char* gg = sb + (size_t)s * 128;
        char* dd = dst0 + buf * 32768;
        #pragma unroll
        for (int i = 0; i < 8; ++i)
            __builtin_amdgcn_global_load_lds(
                (const __attribute__((address_space(1))) unsigned int*)(gg + (size_t)i * 8192),
                (__attribute__((address_space(3))) unsigned int*)(dd + i * 1024),
                16, 0, 0);
    };

    f32x4 acc[8];
    const f32x4 vzero = {0.f, 0.f, 0.f, 0.f};
    #pragma unroll
    for (int i = 0; i < 8; ++i) acc[i] = vzero;

    const unsigned short* qpb_h = qphi + ((size_t)h * 64 + w * 16 + ln) * DDIM;
    const unsigned short* qpb_l = qplo + ((size_t)h * 64 + w * 16 + ln) * DDIM;

    stage(0, 0);
    for (int s = 0; s < 8; ++s) {
        int buf = s & 1;
        __syncthreads();
        if (s + 1 < 8) stage(buf ^ 1, s + 1);
        const char* Bh = arena + buf * 32768;
        const char* Bl = Bh + 16384;
        #pragma unroll
        for (int hh = 0; hh < 2; ++hh) {
            s16x8 ah = *(const s16x8*)(qpb_h + s * 64 + hh * 32 + qd * 8);
            s16x8 al = *(const s16x8*)(qpb_l + s * 64 + hh * 32 + qd * 8);
            int goff = ((hh * 4 + qd) ^ (ln & 7)) * 16;
            #pragma unroll
            for (int ns = 0; ns < 8; ++ns) {
                int ro = (ns * 16 + ln) * 128 + goff;
                s16x8 bh = *(const s16x8*)(Bh + ro);
                s16x8 bl = *(const s16x8*)(Bl + ro);
                acc[ns] = mfma32(ah, bh, acc[ns]);
                acc[ns] = mfma32(ah, bl, acc[ns]);
                acc[ns] = mfma32(al, bh, acc[ns]);
            }
        }
    }
    __syncthreads();
    float* eb = (float*)arena;    // [128 n][69 pad] fp32 = 35 KB
    #pragma unroll
    for (int ns = 0; ns < 8; ++ns)
        #pragma unroll
        for (int r = 0; r < 4; ++r)
            eb[(ns * 16 + ln) * 69 + w * 16 + qd * 4 + r] = acc[ns][r];
    __syncthreads();
    {
        int n = tid >> 1, half = tid & 1;
        size_t base = (((size_t)b * NHEAD + h) * NSEQ + n0 + n) * 64 + half * 32;
        #pragma unroll
        for (int g = 0; g < 8; ++g) {
            ushort4 hv, lv;
            #pragma unroll
            for (int k = 0; k < 4; ++k) {
                float v = eb[n * 69 + half * 32 + g * 4 + k];
                unsigned short hi = f2bf(v);
                ((unsigned short*)&hv)[k] = hi;
                ((unsigned short*)&lv)[k] = f2bf(v - bf2f(hi));
            }
            *(ushort4*)(qhi + base + g * 4) = hv;
            *(ushort4*)(qlo + base + g * 4) = lv;
        }
    }
}

// ---------------------------------------------------------------------------
// Kernel 6: MFMA flash attention. Unchanged from round 3/4.
// ---------------------------------------------------------------------------
__global__ __launch_bounds__(256, 2) void attn_kernel(
    const unsigned short* __restrict__ kkhi, const unsigned short* __restrict__ kklo,
    const unsigned short* __restrict__ vthi, const unsigned short* __restrict__ vtlo,
    const unsigned short* __restrict__ qhi,  const unsigned short* __restrict__ qlo,
    unsigned short* __restrict__ obf)
{
    __shared__ __align__(128) char arena[65536];

    const int tid = threadIdx.x;
    const int w  = tid >> 6;
    const int l  = tid & 63;
    const int qd = l >> 4;
    const int ln = l & 15;
    const int bz = blockIdx.z, hz = blockIdx.y;
    const int n0 = blockIdx.x * 64;

    s16x8 qh[4][2], qlo_[4][2];
    {
        size_t rowb = (((size_t)bz * NHEAD + hz) * NSEQ + n0 + ln) * 64 + qd * 8;
        #pragma unroll
        for (int t = 0; t < 4; ++t)
            #pragma unroll
            for (int c = 0; c < 2; ++c) {
                qh[t][c]   = *(const s16x8*)(qhi + rowb + (size_t)t * 16 * 64 + c * 32);
                qlo_[t][c] = *(const s16x8*)(qlo + rowb + (size_t)t * 16 * 64 + c * 32);
            }
    }

    const int vrow = l >> 3;
    const int gsw  = (l & 7) ^ vrow;
    const char* sb; int rs, ts;
    if      (w == 0) { sb = (const char*)kkhi; rs = 128;  ts = 8192; }
    else if (w == 1) { sb = (const char*)kklo; rs = 128;  ts = 8192; }
    else if (w == 2) { sb = (const char*)vthi; rs = 4096; ts = 128;  }
    else             { sb = (const char*)vtlo; rs = 4096; ts = 128;  }
    sb += (size_t)bz * 262144 + (size_t)vrow * rs + (size_t)gsw * 16;
    char* ldst0 = arena + w * 8192;

    auto stage = [&](int buf, int mt) {
        const char* gg = sb + (size_t)mt * ts;
        char* dst = ldst0 + buf * 32768;
        #pragma unroll
        for (int i = 0; i < 8; ++i) {
            __builtin_amdgcn_global_load_lds(
                (const __attribute__((address_space(1))) unsigned int*)(gg + (size_t)i * 8 * rs),
                (__attribute__((address_space(3))) unsigned int*)(dst + i * 1024),
                16, 0, 0);
        }
    };

    int offK[2], offV[4];
    #pragma unroll
    for (int c = 0; c < 2; ++c)
        offK[c] = (w * 16 + ln) * 128 + (((c * 4 + qd) ^ (ln & 7)) * 16);
    #pragma unroll
    for (int s = 0; s < 4; ++s)
        offV[s] = (s * 16 + ln) * 128 + (((2 * w + (qd >> 1)) ^ (ln & 7)) * 16) + (qd & 1) * 8;

    f32x4 O[4][4];
    const f32x4 vzero = {0.f, 0.f, 0.f, 0.f};
    #pragma unroll
    for (int s = 0; s < 4; ++s)
        #pragma unroll
        for (int t = 0; t < 4; ++t) O[s][t] = vzero;
    float mi[4], li[4];
    #pragma unroll
    for (int t = 0; t < 4; ++t) { mi[t] = -1e30f; li[t] = 0.f; }

    stage(0, 0);

    for (int mt = 0; mt < 32; ++mt) {
        int buf = mt & 1;
        __syncthreads();
        if (mt + 1 < 32) stage(buf ^ 1, mt + 1);
        const char* Kh = arena + buf * 32768;
        const char* Kl = Kh + 8192;
        const char* Vh = Kh + 16384;
        const char* Vl = Kh + 24576;

        s16x8 kh[2], kl[2];
        #pragma unroll
        for (int c = 0; c < 2; ++c) {
            kh[c] = *(const s16x8*)(Kh + offK[c]);
            kl[c] = *(const s16x8*)(Kl + offK[c]);
        }
        f32x4 S[4];
        #pragma unroll
        for (int t = 0; t < 4; ++t) S[t] = vzero;
        #pragma unroll
        for (int c = 0; c < 2; ++c)
            #pragma unroll
            for (int t = 0; t < 4; ++t) {
                S[t] = mfma32(kh[c], qh[t][c],   S[t]);
                S[t] = mfma32(kh[c], qlo_[t][c], S[t]);
                S[t] = mfma32(kl[c], qh[t][c],   S[t]);
            }

        s16x4 pb[4]; float corr[4];
        #pragma unroll
        for (int t = 0; t < 4; ++t) {
            float rmax = fmaxf(fmaxf(S[t][0], S[t][1]), fmaxf(S[t][2], S[t][3]));
            rmax = fmaxf(rmax, __shfl_xor(rmax, 16, 64));
            rmax = fmaxf(rmax, __shfl_xor(rmax, 32, 64));
            float mnew = fmaxf(mi[t], rmax);
            corr[t] = __expf(mi[t] - mnew);
            mi[t] = mnew;
            float p0 = __expf(S[t][0] - mnew);
            float p1 = __expf(S[t][1] - mnew);
            float p2 = __expf(S[t][2] - mnew);
            float p3 = __expf(S[t][3] - mnew);
            float ps = p0 + p1 + p2 + p3;
            ps += __shfl_xor(ps, 16, 64);
            ps += __shfl_xor(ps, 32, 64);
            li[t] = li[t] * corr[t] + ps;
            s16x4 pv;
            pv[0] = (short)f2bf(p0); pv[1] = (short)f2bf(p1);
            pv[2] = (short)f2bf(p2); pv[3] = (short)f2bf(p3);
            pb[t] = pv;
        }
        #pragma unroll
        for (int s = 0; s < 4; ++s)
            #pragma unroll
            for (int t = 0; t < 4; ++t)
                O[s][t] *= corr[t];
        #pragma unroll
        for (int s = 0; s < 4; ++s) {
            s16x4 vh = *(const s16x4*)(Vh + offV[s]);
            s16x4 vl = *(const s16x4*)(Vl + offV[s]);
            #pragma unroll
            for (int t = 0; t < 4; ++t) {
                O[s][t] = mfma16(vh, pb[t], O[s][t]);
                O[s][t] = mfma16(vl, pb[t], O[s][t]);
            }
        }
    }

    float* obuf  = (float*)arena;
    float* mlm   = (float*)(arena + 4608);
    float* mll   = (float*)(arena + 5632);
    float* linvs = (float*)(arena + 6656);

    if (qd == 0) {
        #pragma unroll
        for (int t = 0; t < 4; ++t) {
            mlm[w * 64 + t * 16 + ln] = mi[t];
            mll[w * 64 + t * 16 + ln] = li[t];
        }
    }
    __syncthreads();
    float f[4];
    #pragma unroll
    for (int t = 0; t < 4; ++t) {
        float M = mlm[t * 16 + ln];
        M = fmaxf(M, mlm[64 + t * 16 + ln]);
        M = fmaxf(M, mlm[128 + t * 16 + ln]);
        M = fmaxf(M, mlm[192 + t * 16 + ln]);
        float L = 0.f;
        #pragma unroll
        for (int ww = 0; ww < 4; ++ww)
            L += mll[ww * 64 + t * 16 + ln] * __expf(mlm[ww * 64 + t * 16 + ln] - M);
        f[t] = __expf(mi[t] - M);
        if (w == 0 && qd == 0) linvs[t * 16 + ln] = 1.0f / L;
    }

    #pragma unroll
    for (int t = 0; t < 4; ++t) {
        #pragma unroll
        for (int r = 0; r < 4; ++r) {
            __syncthreads();
            #pragma unroll
            for (int s = 0; s < 4; ++s) {
                if (((w + r) & 3) == s) {
                    f32x4 val = O[s][t] * f[t];
                    float* dst = obuf + (s * 16 + qd * 4) * 17 + ln;
                    if (r == 0) {
                        dst[0]  = val[0]; dst[17] = val[1];
                        dst[34] = val[2]; dst[51] = val[3];
                    } else {
                        dst[0]  += val[0]; dst[17] += val[1];
                        dst[34] += val[2]; dst[51] += val[3];
                    }
                }
            }
        }
        __syncthreads();
        int vq = tid & 15, nl = tid >> 4;
        float il = linvs[t * 16 + nl];
        ushort4 u4;
        u4.x = f2bf(obuf[(vq * 4 + 0) * 17 + nl] * il);
        u4.y = f2bf(obuf[(vq * 4 + 1) * 17 + nl] * il);
        u4.z = f2bf(obuf[(vq * 4 + 2) * 17 + nl] * il);
        u4.w = f2bf(obuf[(vq * 4 + 3) * 17 + nl] * il);
        *(ushort4*)(obf + (((size_t)bz * NSEQ + n0 + t * 16 + nl) * 512) + hz * 64 + vq * 4) = u4;
    }
}

// ---------------------------------------------------------------------------
// Kernel 7: output projection, MFMA. Unchanged from round 4.
// ---------------------------------------------------------------------------
__global__ __launch_bounds__(256, 2) void out_proj_kernel(
    const unsigned short* __restrict__ obf,
    const unsigned short* __restrict__ ophi, const unsigned short* __restrict__ oplo,
    float* __restrict__ out)
{
    __shared__ __align__(128) char arena[32768];
    const int tid = threadIdx.x;
    const int w = tid >> 6, l = tid & 63;
    const int qd = l >> 4, ln = l & 15;
    const int b = blockIdx.z, d0 = blockIdx.y * 64;
    const int n0 = blockIdx.x * 128;
    const int vrow = l >> 3, gsw = (l & 7) ^ vrow;

    const char* sb = (const char*)obf
        + ((size_t)(b * NSEQ + n0 + w * 32) * 512) * 2
        + (size_t)vrow * 1024 + (size_t)gsw * 16;
    char* dst0 = arena + w * 32 * 128;

    auto stage = [&](int buf, int s) {
        const char* gg = sb + (size_t)s * 128;
        char* dd = dst0 + buf * 16384;
        #pragma unroll
        for (int i = 0; i < 4; ++i)
            __builtin_amdgcn_global_load_lds(
                (const __attribute__((address_space(1))) unsigned int*)(gg + (size_t)i * 8192),
                (__attribute__((address_space(3))) unsigned int*)(dd + i * 1024),
                16, 0, 0);
    };

    f32x4 acc[8];
    const f32x4 vzero = {0.f, 0.f, 0.f, 0.f};
    #pragma unroll
    for (int i = 0; i < 8; ++i) acc[i] = vzero;

    const unsigned short* oph = ophi + (size_t)(d0 + w * 16 + ln) * 512;
    const unsigned short* opl = oplo + (size_t)(d0 + w * 16 + ln) * 512;

    stage(0, 0);
    for (int s = 0; s < 8; ++s) {
        int buf = s & 1;
        __syncthreads();
        if (s + 1 < 8) stage(buf ^ 1, s + 1);
        const char* Bt = arena + buf * 16384;
        #pragma unroll
        for (int hh = 0; hh < 2; ++hh) {
            s16x8 ah = *(const s16x8*)(oph + s * 64 + hh * 32 + qd * 8);
            s16x8 al = *(const s16x8*)(opl + s * 64 + hh * 32 + qd * 8);
            int goff = ((hh * 4 + qd) ^ (ln & 7)) * 16;
            #pragma unroll
            for (int ns = 0; ns < 8; ++ns) {
                s16x8 bb = *(const s16x8*)(Bt + (ns * 16 + ln) * 128 + goff);
                acc[ns] = mfma32(ah, bb, acc[ns]);
                acc[ns] = mfma32(al, bb, acc[ns]);
            }
        }
    }
    #pragma unroll
    for (int ns = 0; ns < 8; ++ns)
        #pragma unroll
        for (int r = 0; r < 4; ++r)
            out[((size_t)b * DDIM + d0 + w * 16 + qd * 4 + r) * NSEQ
                + n0 + ns * 16 + ln] = acc[ns][r];
}

// ---------------------------------------------------------------------------
extern "C" void kernel_launch(void* const* d_in, const int* in_sizes, int n_in,
                              void* d_out, int out_size, void* d_ws, size_t ws_size,
                              hipStream_t stream) {
    const float* x  = (const float*)d_in[0];   // (2,512,2048)
    const float* qp = (const float*)d_in[1];   // (8,64,512)
    const float* kp = (const float*)d_in[2];   // (512,64)
    const float* vp = (const float*)d_in[3];   // (512,64)
    const float* op = (const float*)d_in[4];   // (512,8,64)
    float* out = (float*)d_out;                // (2,512,2048)

    // Workspace (shorts), ~21.3 MB. obf aliases xthi (dead after projections).
    unsigned short* ws    = (unsigned short*)d_ws;
    unsigned short* kkhi  = ws;                   // 262144
    unsigned short* kklo  = kkhi + 262144;
    unsigned short* vthi  = kklo + 262144;
    unsigned short* vtlo  = vthi + 262144;
    unsigned short* qphi  = vtlo + 262144;
    unsigned short* qplo  = qphi + 262144;
    unsigned short* ophi  = qplo + 262144;
    unsigned short* oplo  = ophi + 262144;
    unsigned short* kpthi = oplo + 262144;        // 32768
    unsigned short* kptlo = kpthi + 32768;
    unsigned short* vpthi = kptlo + 32768;
    unsigned short* vptlo = vpthi + 32768;
    unsigned short* xthi  = vptlo + 32768;        // 2097152
    unsigned short* xtlo  = xthi + 2097152;
    unsigned short* qhi   = xtlo + 2097152;
    unsigned short* qlo   = qhi + 2097152;
    unsigned short* obf   = xthi;                 // alias

    hipLaunchKernelGGL(xt_kernel,       dim3(32, 8, 2),  dim3(256), 0, stream,
                       x, xthi, xtlo);
    hipLaunchKernelGGL(wconv_kernel,    dim3(256, 2),    dim3(256), 0, stream,
                       qp, op, qphi, qplo, ophi, oplo);
    hipLaunchKernelGGL(kvw_kernel,      dim3(8, 2),      dim3(256), 0, stream,
                       kp, vp, kpthi, kptlo, vpthi, vptlo);
    hipLaunchKernelGGL(kv_proj_kernel,  dim3(32, 2),     dim3(256), 0, stream,
                       xthi, xtlo, kpthi, kptlo, vpthi, vptlo,
                       kkhi, kklo, vthi, vtlo);
    hipLaunchKernelGGL(q_proj_kernel,   dim3(16, 8, 2),  dim3(256), 0, stream,
                       xthi, xtlo, qphi, qplo, qhi, qlo);
    hipLaunchKernelGGL(attn_kernel,     dim3(32, 8, 2),  dim3(256), 0, stream,
                       kkhi, kklo, vthi, vtlo, qhi, qlo, obf);
    hipLaunchKernelGGL(out_proj_kernel, dim3(16, 8, 2),  dim3(256), 0, stream,
                       obf, ophi, oplo, out);
}